// Round 11
// baseline (230.599 us; speedup 1.0000x reference)
//
#include <hip/hip_runtime.h>

#define DIM_ 768
#define MID_ 96

typedef float f32x4 __attribute__((ext_vector_type(4)));
typedef __bf16 bf16x8 __attribute__((ext_vector_type(8)));
typedef __bf16 bf16x4 __attribute__((ext_vector_type(4)));

// ---------------------------------------------------------------------------
// K_prep: fused weight prep.
// Blocks [0,48): fold LN scale into down/down1 weights; sw/cb constants.
// Blocks [48,141): bf16-cast up_w, pw_w; zero gvec partials.
// ---------------------------------------------------------------------------
__global__ __launch_bounds__(256) void k_prep(
        const float* __restrict__ dw, const float* __restrict__ db,
        const float* __restrict__ lnw0, const float* __restrict__ lnb0,
        const float* __restrict__ d1w, const float* __restrict__ d1b,
        const float* __restrict__ lnw1, const float* __restrict__ lnb1,
        __bf16* __restrict__ wln0, __bf16* __restrict__ wln1,
        float* __restrict__ swcb,
        const float* __restrict__ uw, const float* __restrict__ pw,
        __bf16* __restrict__ bup, __bf16* __restrict__ bpw,
        float* __restrict__ part) {
    if (blockIdx.x >= 48) {
        const int t = (blockIdx.x - 48) * 256 + threadIdx.x;
        const float* src;
        __bf16* dst;
        int i;
        if (t < 18432)      { src = uw; dst = bup; i = t; }
        else if (t < 23040) { src = pw; dst = bpw; i = t - 18432; }
        else if (t < 23808) { part[t - 23040] = 0.f; return; }
        else return;
        float4 v = reinterpret_cast<const float4*>(src)[i];
        bf16x4 o;
        o[0] = (__bf16)v.x; o[1] = (__bf16)v.y;
        o[2] = (__bf16)v.z; o[3] = (__bf16)v.w;
        *reinterpret_cast<bf16x4*>(dst + (size_t)i * 4) = o;
        return;
    }
    const int wid = blockIdx.x * 4 + (threadIdx.x >> 6);
    const int lane = threadIdx.x & 63;
    const int mat = wid >= 96;
    const int n = mat ? wid - 96 : wid;
    const float* W   = mat ? d1w : dw;
    const float* bia = mat ? d1b : db;
    const float* lw  = mat ? lnw1 : lnw0;
    const float* lb  = mat ? lnb1 : lnb0;
    __bf16* dst = mat ? wln1 : wln0;
    float sacc = 0.f, cacc = 0.f;
#pragma unroll
    for (int j = 0; j < 12; ++j) {
        const int k = j * 64 + lane;
        const float w = W[(size_t)n * DIM_ + k];
        const float val = w * lw[k];
        const __bf16 bv = (__bf16)val;
        dst[(size_t)n * DIM_ + k] = bv;
        sacc += (float)bv;
        cacc += lb[k] * w;
    }
#pragma unroll
    for (int m = 1; m < 64; m <<= 1) {
        sacc += __shfl_xor(sacc, m, 64);
        cacc += __shfl_xor(cacc, m, 64);
    }
    if (lane == 0) {
        swcb[mat * 192 + n] = sacc;               // sw
        swcb[mat * 192 + 96 + n] = cacc + bia[n]; // cb
    }
}

// ---------------------------------------------------------------------------
// K_lnorm v2: one row per wave, NO loop (r10's grid-stride serialized the
// shfl chain 8x per wave; the r1 k_stats shape -- fresh wave per row --
// demonstrated ~5.9 TB/s). Reads fp32 row, butterfly stats, writes
// bf16((x-mu)*rstd). lnw/lnb stay folded in W (k_prep).
// ---------------------------------------------------------------------------
__global__ __launch_bounds__(256) void k_lnorm(
        const float* __restrict__ xsrc, const float* __restrict__ tsrc,
        __bf16* __restrict__ xn, __bf16* __restrict__ tn) {
    const int lane = threadIdx.x & 63;
    const int row = blockIdx.x * 4 + (threadIdx.x >> 6);   // 0..65535
    const int half = row >> 15;
    const int r = row & 32767;
    const float* rp = (half ? tsrc : xsrc) + (size_t)r * DIM_;
    __bf16* dp = (half ? tn : xn) + (size_t)r * DIM_;
    const float4 v0 = *reinterpret_cast<const float4*>(rp + lane * 4);
    const float4 v1 = *reinterpret_cast<const float4*>(rp + 256 + lane * 4);
    const float4 v2 = *reinterpret_cast<const float4*>(rp + 512 + lane * 4);
    float s = v0.x + v0.y + v0.z + v0.w + v1.x + v1.y + v1.z + v1.w +
              v2.x + v2.y + v2.z + v2.w;
    float sq = v0.x * v0.x + v0.y * v0.y + v0.z * v0.z + v0.w * v0.w +
               v1.x * v1.x + v1.y * v1.y + v1.z * v1.z + v1.w * v1.w +
               v2.x * v2.x + v2.y * v2.y + v2.z * v2.z + v2.w * v2.w;
#pragma unroll
    for (int m = 1; m < 64; m <<= 1) {
        s += __shfl_xor(s, m, 64);
        sq += __shfl_xor(sq, m, 64);
    }
    const float mean = s * (1.f / 768.f);
    const float rstd = rsqrtf(sq * (1.f / 768.f) - mean * mean + 1e-6f);
    bf16x4 o0, o1, o2;
    o0[0] = (__bf16)((v0.x - mean) * rstd);
    o0[1] = (__bf16)((v0.y - mean) * rstd);
    o0[2] = (__bf16)((v0.z - mean) * rstd);
    o0[3] = (__bf16)((v0.w - mean) * rstd);
    o1[0] = (__bf16)((v1.x - mean) * rstd);
    o1[1] = (__bf16)((v1.y - mean) * rstd);
    o1[2] = (__bf16)((v1.z - mean) * rstd);
    o1[3] = (__bf16)((v1.w - mean) * rstd);
    o2[0] = (__bf16)((v2.x - mean) * rstd);
    o2[1] = (__bf16)((v2.y - mean) * rstd);
    o2[2] = (__bf16)((v2.z - mean) * rstd);
    o2[3] = (__bf16)((v2.w - mean) * rstd);
    *reinterpret_cast<bf16x4*>(dp + lane * 4) = o0;
    *reinterpret_cast<bf16x4*>(dp + 256 + lane * 4) = o1;
    *reinterpret_cast<bf16x4*>(dp + 512 + lane * 4) = o2;
}

// ---------------------------------------------------------------------------
// K_gemm96 v2: bf16 GEMM, W LDS-resident in fragment order, no K-loop
// barriers. Depth-8 named-register prefetch (128 B/lane in flight; r10's
// depth-4 was MLP-starved). 16 waves x 16 rows, N=96. VGPR ~70 of 128
// budget at waves_per_eu(4,4).
// ---------------------------------------------------------------------------
__global__ __launch_bounds__(1024)
__attribute__((amdgpu_waves_per_eu(4, 4)))
void k_gemm96(const __bf16* __restrict__ xn, const __bf16* __restrict__ tn,
        const __bf16* __restrict__ wln0, const __bf16* __restrict__ wln1,
        const float* __restrict__ swcb, __bf16* __restrict__ xemb,
        __bf16* __restrict__ temb, float* __restrict__ part) {
    extern __shared__ __bf16 Wp[];   // 96*768 = 147456 B, fragment order
    const int t = threadIdx.x;
    const int half = blockIdx.x >> 7;
    const int mb = blockIdx.x & 127;
    const __bf16* src = half ? tn : xn;
    const __bf16* wln = half ? wln1 : wln0;
    const float* sc = swcb + half * 192;
    __bf16* outb = half ? temb : xemb;
#pragma unroll
    for (int i = 0; i < 9; ++i) {
        const int idx = t + i * 1024;
        const int ls = idx & 63;
        const int rem = idx >> 6;              // kt*6 + f
        const int kt = rem / 6;
        const int f = rem - kt * 6;
        const int row = f * 16 + (ls & 15);
        const int col = kt * 32 + (ls >> 4) * 8;
        *reinterpret_cast<bf16x8*>(Wp + (size_t)idx * 8) =
            *reinterpret_cast<const bf16x8*>(wln + (size_t)row * DIM_ + col);
    }
    __syncthreads();

    const int lane = t & 63, wave = t >> 6;   // 16 waves, 16 rows each
    const int l15 = lane & 15, l4 = lane >> 4;
    const int row = mb * 256 + wave * 16 + l15;
    const __bf16* rp = src + (size_t)row * DIM_ + l4 * 8;
    f32x4 acc[6] = {};

    bf16x8 p0 = *reinterpret_cast<const bf16x8*>(rp + 0);
    bf16x8 p1 = *reinterpret_cast<const bf16x8*>(rp + 32);
    bf16x8 p2 = *reinterpret_cast<const bf16x8*>(rp + 64);
    bf16x8 p3 = *reinterpret_cast<const bf16x8*>(rp + 96);
    bf16x8 p4 = *reinterpret_cast<const bf16x8*>(rp + 128);
    bf16x8 p5 = *reinterpret_cast<const bf16x8*>(rp + 160);
    bf16x8 p6 = *reinterpret_cast<const bf16x8*>(rp + 192);
    bf16x8 p7 = *reinterpret_cast<const bf16x8*>(rp + 224);

    auto consume = [&](bf16x8& p, int kt) {
        const bf16x8 a = p;
        if (kt + 8 < 24)
            p = *reinterpret_cast<const bf16x8*>(rp + (kt + 8) * 32);
        const __bf16* bp = Wp + ((size_t)(kt * 6) * 64 + lane) * 8;
#pragma unroll
        for (int f = 0; f < 6; ++f) {
            bf16x8 b = *reinterpret_cast<const bf16x8*>(bp + (size_t)f * 64 * 8);
            acc[f] = __builtin_amdgcn_mfma_f32_16x16x32_bf16(a, b, acc[f], 0, 0, 0);
        }
    };
#pragma unroll
    for (int kb = 0; kb < 24; kb += 8) {
        consume(p0, kb + 0);
        consume(p1, kb + 1);
        consume(p2, kb + 2);
        consume(p3, kb + 3);
        consume(p4, kb + 4);
        consume(p5, kb + 5);
        consume(p6, kb + 6);
        consume(p7, kb + 7);
    }

    const int orow0 = mb * 256 + wave * 16 + l4 * 4;
    const int batch = mb >> 4;     // 16 blocks per image
#pragma unroll
    for (int f = 0; f < 6; ++f) {
        const int col = f * 16 + l15;
        const float cbc = sc[96 + col];
        float colsum = 0.f;
#pragma unroll
        for (int rr = 0; rr < 4; ++rr) {
            const float val = acc[f][rr] + cbc;
            outb[(size_t)(orow0 + rr) * MID_ + col] = (__bf16)val;
            colsum += val;
        }
        if (half == 0) {
            colsum += __shfl_xor(colsum, 16, 64);
            colsum += __shfl_xor(colsum, 32, 64);
            if (l4 == 0) atomicAdd(&part[batch * MID_ + col], colsum);
        }
    }
}

// ---------------------------------------------------------------------------
// K_downf (fallback when ws too small for fast path): r8 version.
// ---------------------------------------------------------------------------
__global__ __launch_bounds__(1024)
__attribute__((amdgpu_waves_per_eu(4, 4)))
void k_downf(
        const float* __restrict__ xsrc, const float* __restrict__ tsrc,
        const __bf16* __restrict__ wln0, const __bf16* __restrict__ wln1,
        const float* __restrict__ swcb, __bf16* __restrict__ xemb,
        __bf16* __restrict__ temb, float* __restrict__ part) {
    extern __shared__ __bf16 Wp[];
    const int t = threadIdx.x;
    const int half = blockIdx.x >> 7;
    const int mb = blockIdx.x & 127;
    const float* src = half ? tsrc : xsrc;
    const __bf16* wln = half ? wln1 : wln0;
    const float* sc = swcb + half * 192;
    __bf16* outb = half ? temb : xemb;
#pragma unroll
    for (int i = 0; i < 9; ++i) {
        const int idx = t + i * 1024;
        const int ls = idx & 63;
        const int rem = idx >> 6;
        const int kt = rem / 6;
        const int f = rem - kt * 6;
        const int row = f * 16 + (ls & 15);
        const int col = kt * 32 + (ls >> 4) * 8;
        *reinterpret_cast<bf16x8*>(Wp + (size_t)idx * 8) =
            *reinterpret_cast<const bf16x8*>(wln + (size_t)row * DIM_ + col);
    }
    __syncthreads();
    const int lane = t & 63, wave = t >> 6;
    const int l15 = lane & 15, l4 = lane >> 4;
    const int row = mb * 256 + wave * 16 + l15;
    const float* rp = src + (size_t)row * DIM_ + l4 * 8;
    float s = 0.f, sq = 0.f;
    f32x4 acc[6] = {};
    auto cvt = [&](const float4& v0, const float4& v1) -> bf16x8 {
        s += v0.x + v0.y + v0.z + v0.w + v1.x + v1.y + v1.z + v1.w;
        sq += v0.x * v0.x + v0.y * v0.y + v0.z * v0.z + v0.w * v0.w +
              v1.x * v1.x + v1.y * v1.y + v1.z * v1.z + v1.w * v1.w;
        bf16x8 a;
        a[0] = (__bf16)v0.x; a[1] = (__bf16)v0.y;
        a[2] = (__bf16)v0.z; a[3] = (__bf16)v0.w;
        a[4] = (__bf16)v1.x; a[5] = (__bf16)v1.y;
        a[6] = (__bf16)v1.z; a[7] = (__bf16)v1.w;
        return a;
    };
    auto consume = [&](const bf16x8& a, int kt) {
        const __bf16* bp = Wp + ((size_t)(kt * 6) * 64 + lane) * 8;
#pragma unroll
        for (int f = 0; f < 6; ++f) {
            bf16x8 b = *reinterpret_cast<const bf16x8*>(bp + (size_t)f * 64 * 8);
            acc[f] = __builtin_amdgcn_mfma_f32_16x16x32_bf16(a, b, acc[f], 0, 0, 0);
        }
    };
    float4 w0a = *reinterpret_cast<const float4*>(rp + 0);
    float4 w0b = *reinterpret_cast<const float4*>(rp + 4);
    float4 w1a = *reinterpret_cast<const float4*>(rp + 32);
    float4 w1b = *reinterpret_cast<const float4*>(rp + 36);
    bf16x8 a0 = cvt(w0a, w0b);
    bf16x8 a1 = cvt(w1a, w1b);
    w0a = *reinterpret_cast<const float4*>(rp + 64);
    w0b = *reinterpret_cast<const float4*>(rp + 68);
    w1a = *reinterpret_cast<const float4*>(rp + 96);
    w1b = *reinterpret_cast<const float4*>(rp + 100);
#pragma unroll
    for (int kt = 0; kt < 24; kt += 2) {
        consume(a0, kt);
        if (kt + 2 < 24) {
            a0 = cvt(w0a, w0b);
            if (kt + 4 < 24) {
                w0a = *reinterpret_cast<const float4*>(rp + (kt + 4) * 32);
                w0b = *reinterpret_cast<const float4*>(rp + (kt + 4) * 32 + 4);
            }
        }
        consume(a1, kt + 1);
        if (kt + 3 < 24) {
            a1 = cvt(w1a, w1b);
            if (kt + 5 < 24) {
                w1a = *reinterpret_cast<const float4*>(rp + (kt + 5) * 32);
                w1b = *reinterpret_cast<const float4*>(rp + (kt + 5) * 32 + 4);
            }
        }
    }
    s += __shfl_xor(s, 16, 64); sq += __shfl_xor(sq, 16, 64);
    s += __shfl_xor(s, 32, 64); sq += __shfl_xor(sq, 32, 64);
    const float mean = s * (1.f / 768.f);
    const float rstd = rsqrtf(sq * (1.f / 768.f) - mean * mean + 1e-6f);
    const float mur = mean * rstd;
    float rstd_r[4], mur_r[4];
#pragma unroll
    for (int rr = 0; rr < 4; ++rr) {
        rstd_r[rr] = __shfl(rstd, l4 * 4 + rr, 64);
        mur_r[rr]  = __shfl(mur,  l4 * 4 + rr, 64);
    }
    const int orow0 = mb * 256 + wave * 16 + l4 * 4;
    const int batch = mb >> 4;
#pragma unroll
    for (int f = 0; f < 6; ++f) {
        const int col = f * 16 + l15;
        const float swc = sc[col];
        const float cbc = sc[96 + col];
        float colsum = 0.f;
#pragma unroll
        for (int rr = 0; rr < 4; ++rr) {
            const float val = acc[f][rr] * rstd_r[rr] - mur_r[rr] * swc + cbc;
            outb[(size_t)(orow0 + rr) * MID_ + col] = (__bf16)val;
            colsum += val;
        }
        if (half == 0) {
            colsum += __shfl_xor(colsum, 16, 64);
            colsum += __shfl_xor(colsum, 32, 64);
            if (l4 == 0) atomicAdd(&part[batch * MID_ + col], colsum);
        }
    }
}

// ---------------------------------------------------------------------------
// K_mlp: gvec mean from part, MLP (96->24 relu ->4), softmax -> wts [8,4]
// ---------------------------------------------------------------------------
__global__ __launch_bounds__(128) void k_mlp(const float* __restrict__ part,
        const float* __restrict__ m1w, const float* __restrict__ m1b,
        const float* __restrict__ m2w, const float* __restrict__ m2b,
        float* __restrict__ wts) {
    const int b = blockIdx.x, t = threadIdx.x;
    __shared__ float gv[96];
    __shared__ float hid[24];
    __shared__ float lg[4];
    if (t < 96) gv[t] = part[b * MID_ + t] * (1.f / 4096.f);
    __syncthreads();
    if (t < 24) {
        float s = m1b[t];
        for (int c = 0; c < 96; ++c) s += gv[c] * m1w[t * 96 + c];
        hid[t] = fmaxf(s, 0.f);
    }
    __syncthreads();
    if (t < 4) {
        float s = m2b[t];
        for (int j = 0; j < 24; ++j) s += hid[j] * m2w[t * 24 + j];
        lg[t] = s;
    }
    __syncthreads();
    if (t < 4) {
        const float m = fmaxf(fmaxf(lg[0], lg[1]), fmaxf(lg[2], lg[3]));
        const float e = __expf(lg[t] - m);
        const float sum = __expf(lg[0] - m) + __expf(lg[1] - m) +
                          __expf(lg[2] - m) + __expf(lg[3] - m);
        wts[b * 4 + t] = e / sum;
    }
}

// ---------------------------------------------------------------------------
// K_dwconv: depthwise 3x3 conv (zero pad) + SiLU. temb bf16 -> y bf16.
// ---------------------------------------------------------------------------
__global__ __launch_bounds__(256) void k_dwconv(const __bf16* __restrict__ temb,
        const float* __restrict__ dww, const float* __restrict__ dwb,
        __bf16* __restrict__ y) {
    __shared__ float wls[96 * 9];
    __shared__ float bls[96];
    const int t = threadIdx.x;
    for (int i = t; i < 96 * 9; i += 256) wls[i] = dww[i];
    if (t < 96) bls[t] = dwb[t];
    __syncthreads();
    const int b = blockIdx.x >> 6, h = blockIdx.x & 63;
    const __bf16* base = temb + (size_t)b * 4096 * MID_;
    for (int o = t; o < 64 * 96; o += 256) {
        const int w = o / 96;
        const int c = o - w * 96;
        float acc = bls[c];
#pragma unroll
        for (int dh = 0; dh < 3; ++dh) {
            const int hh = h + dh - 1;
            if (hh < 0 || hh > 63) continue;
#pragma unroll
            for (int dw = 0; dw < 3; ++dw) {
                const int ww = w + dw - 1;
                if (ww < 0 || ww > 63) continue;
                acc += (float)base[((size_t)hh * 64 + ww) * MID_ + c] *
                       wls[c * 9 + dh * 3 + dw];
            }
        }
        y[((size_t)(b * 64 + h) * 64 + w) * MID_ + c] =
            (__bf16)(acc / (1.f + __expf(-acc)));
    }
}

// ---------------------------------------------------------------------------
// K_style: style GEMM (y @ pw_w^T + pw_b) fused with modulation:
// common = x_emb * (1 + gamma) + beta -> bf16. K=96 fully staged, 1 barrier.
// ---------------------------------------------------------------------------
__global__ __launch_bounds__(256) void k_style(const __bf16* __restrict__ y,
        const __bf16* __restrict__ wpw, const float* __restrict__ pwb,
        const __bf16* __restrict__ xemb, __bf16* __restrict__ common) {
    __shared__ bf16x8 As[64][13];
    __shared__ bf16x8 Bs[192][13];
    const int t = threadIdx.x;
    const int row0 = blockIdx.x * 64;
    for (int idx = t; idx < 768; idx += 256) {
        const int rr = idx / 12, q = idx - rr * 12;
        As[rr][q] = *reinterpret_cast<const bf16x8*>(
            y + (size_t)(row0 + rr) * MID_ + q * 8);
    }
    for (int idx = t; idx < 2304; idx += 256) {
        const int rr = idx / 12, q = idx - rr * 12;
        Bs[rr][q] = *reinterpret_cast<const bf16x8*>(
            wpw + (size_t)rr * MID_ + q * 8);
    }
    __syncthreads();
    const int lane = t & 63, wave = t >> 6;
    const int l15 = lane & 15, l4 = lane >> 4;
    f32x4 acc[12] = {};
    const int ar = wave * 16 + l15;
#pragma unroll
    for (int kt = 0; kt < 3; ++kt) {
        bf16x8 a = As[ar][kt * 4 + l4];
#pragma unroll
        for (int f = 0; f < 12; ++f) {
            bf16x8 b = Bs[f * 16 + l15][kt * 4 + l4];
            acc[f] = __builtin_amdgcn_mfma_f32_16x16x32_bf16(a, b, acc[f], 0, 0, 0);
        }
    }
    const int orow = row0 + wave * 16 + l4 * 4;
#pragma unroll
    for (int f = 0; f < 6; ++f) {
        const int col = f * 16 + l15;
        const float pbg = pwb[col];
        const float pbb = pwb[col + 96];
#pragma unroll
        for (int rr = 0; rr < 4; ++rr) {
            const float g = acc[f][rr] + pbg;
            const float bt = acc[f + 6][rr] + pbb;
            const float xe = (float)xemb[(size_t)(orow + rr) * MID_ + col];
            common[(size_t)(orow + rr) * MID_ + col] = (__bf16)(xe * (1.f + g) + bt);
        }
    }
}

// ---------------------------------------------------------------------------
// K_circ: circular 7x7 conv (== rfft2/irfft2 product). dyn built in LDS.
// ---------------------------------------------------------------------------
__global__ __launch_bounds__(192) void k_circ(const __bf16* __restrict__ common,
        const float* __restrict__ wts, const float* __restrict__ basis,
        __bf16* __restrict__ outc) {
    __shared__ float dyn[49][96];
    const int t = threadIdx.x;
    const int b = blockIdx.x >> 7;
    const int h = (blockIdx.x >> 1) & 63;
    const int wslice = blockIdx.x & 1;
    const float w0 = wts[b * 4 + 0], w1 = wts[b * 4 + 1];
    const float w2 = wts[b * 4 + 2], w3 = wts[b * 4 + 3];
    for (int idx = t; idx < 4704; idx += 192) {
        const int c = idx / 49;
        const int pq = idx - c * 49;
        const size_t off = (size_t)c * 49 + pq;
        dyn[pq][c] = w0 * basis[off] + w1 * basis[off + 4704] +
                     w2 * basis[off + 9408] + w3 * basis[off + 14112];
    }
    __syncthreads();
    const int c = t % 96;
    const int wg = t / 96;
    const int wbase = wslice * 32 + wg * 16;
    const __bf16* cb = common + (size_t)b * 4096 * MID_ + c;
    float acc[16] = {};
#pragma unroll 1
    for (int p = 0; p < 7; ++p) {
        const int hh = (h + 3 - p) & 63;
        const __bf16* rp = cb + (size_t)hh * 64 * MID_;
        float dynr[7];
#pragma unroll
        for (int q = 0; q < 7; ++q) dynr[q] = dyn[p * 7 + q][c];
#pragma unroll
        for (int i = 0; i < 22; ++i) {
            const int ww = (wbase - 3 + i) & 63;
            const float cm = (float)rp[(size_t)ww * MID_];
#pragma unroll
            for (int q = 0; q < 7; ++q) {
                const int li = i + q - 6;
                if (li >= 0 && li < 16) acc[li] += dynr[q] * cm;
            }
        }
    }
    const size_t obase = ((size_t)(b * 64 + h) * 64 + wbase) * MID_ + c;
#pragma unroll
    for (int li = 0; li < 16; ++li)
        outc[obase + (size_t)li * MID_] = (__bf16)acc[li];
}

// ---------------------------------------------------------------------------
// K_up: out = a_in[32768,96] @ up_w_bf16[768,96]^T + up_b + x  (fp32 out)
// ---------------------------------------------------------------------------
__global__ __launch_bounds__(256) void k_up(const __bf16* __restrict__ a_in,
        const __bf16* __restrict__ wbf, const float* __restrict__ upb,
        const float* __restrict__ x, float* __restrict__ out) {
    __shared__ bf16x8 As[128][13];
    __shared__ bf16x8 Ws[96][13];
    const int t = threadIdx.x;
    const int mt = blockIdx.x >> 3, nt = blockIdx.x & 7;
    const int row0 = mt * 128, col0 = nt * 96;
    for (int idx = t; idx < 1536; idx += 256) {
        const int rr = idx / 12, q = idx - rr * 12;
        As[rr][q] = *reinterpret_cast<const bf16x8*>(
            a_in + (size_t)(row0 + rr) * MID_ + q * 8);
    }
    for (int idx = t; idx < 1152; idx += 256) {
        const int rr = idx / 12, q = idx - rr * 12;
        Ws[rr][q] = *reinterpret_cast<const bf16x8*>(
            wbf + (size_t)(col0 + rr) * MID_ + q * 8);
    }
    __syncthreads();
    const int lane = t & 63, wave = t >> 6;
    const int l15 = lane & 15, l4 = lane >> 4;
    f32x4 acc[2][6] = {};
#pragma unroll
    for (int kt = 0; kt < 3; ++kt) {
        bf16x8 a0 = As[wave * 32 + l15][kt * 4 + l4];
        bf16x8 a1 = As[wave * 32 + 16 + l15][kt * 4 + l4];
#pragma unroll
        for (int f = 0; f < 6; ++f) {
            bf16x8 b = Ws[f * 16 + l15][kt * 4 + l4];
            acc[0][f] = __builtin_amdgcn_mfma_f32_16x16x32_bf16(a0, b, acc[0][f], 0, 0, 0);
            acc[1][f] = __builtin_amdgcn_mfma_f32_16x16x32_bf16(a1, b, acc[1][f], 0, 0, 0);
        }
    }
#pragma unroll
    for (int mr = 0; mr < 2; ++mr) {
        const int orow = row0 + wave * 32 + mr * 16 + l4 * 4;
#pragma unroll
        for (int f = 0; f < 6; ++f) {
            const int col = col0 + f * 16 + l15;
            const float ub = upb[col];
#pragma unroll
            for (int rr = 0; rr < 4; ++rr) {
                const size_t idx = (size_t)(orow + rr) * DIM_ + col;
                out[idx] = acc[mr][f][rr] + ub + x[idx];
            }
        }
    }
}

// ---------------------------------------------------------------------------
extern "C" void kernel_launch(void* const* d_in, const int* in_sizes, int n_in,
                              void* d_out, int out_size, void* d_ws, size_t ws_size,
                              hipStream_t stream) {
    (void)in_sizes; (void)n_in; (void)out_size;
    const float* x      = (const float*)d_in[0];
    const float* tt     = (const float*)d_in[1];
    const float* ln_w   = (const float*)d_in[2];
    const float* ln_b   = (const float*)d_in[3];
    const float* down_w = (const float*)d_in[4];
    const float* down_b = (const float*)d_in[5];
    const float* ln1_w  = (const float*)d_in[6];
    const float* ln1_b  = (const float*)d_in[7];
    const float* down1_w= (const float*)d_in[8];
    const float* down1_b= (const float*)d_in[9];
    const float* dw_w   = (const float*)d_in[10];
    const float* dw_b   = (const float*)d_in[11];
    const float* pw_w   = (const float*)d_in[12];
    const float* pw_b   = (const float*)d_in[13];
    const float* m1w    = (const float*)d_in[14];
    const float* m1b    = (const float*)d_in[15];
    const float* m2w    = (const float*)d_in[16];
    const float* m2b    = (const float*)d_in[17];
    const float* basis  = (const float*)d_in[18];
    const float* up_w   = (const float*)d_in[19];
    const float* up_b   = (const float*)d_in[20];
    float* out = (float*)d_out;
    char* ws = (char*)d_ws;

    // workspace layout (bytes)
    __bf16* wln_down  = (__bf16*)(ws + 0);          // 96*768*2  = 147456
    __bf16* wln_down1 = (__bf16*)(ws + 147456);
    __bf16* wbf_up    = (__bf16*)(ws + 294912);     // 768*96*2
    __bf16* wbf_pw    = (__bf16*)(ws + 442368);     // 192*96*2 = 36864
    float*  part      = (float*)(ws + 479232);      // 8*96*4 = 3072
    float*  wts       = (float*)(ws + 482304);      // 32*4
    float*  swcb      = (float*)(ws + 482560);      // 2*192*4 = 1536
    __bf16* x_emb     = (__bf16*)(ws + 524288);     // 32768*96*2 = 6291456
    __bf16* t_emb     = (__bf16*)(ws + 6815744);
    __bf16* ybuf      = (__bf16*)(ws + 13107200);
    __bf16* common    = (__bf16*)(ws + 19398656);
    __bf16* convout   = (__bf16*)(ws + 25690112);
    __bf16* xn        = (__bf16*)(ws + 31981568);   // 32768*768*2 = 50331648
    __bf16* tn        = (__bf16*)(ws + 82313216);   // 50331648
    const size_t FAST_NEED = 82313216ULL + 50331648ULL;   // 132644864
    const bool fast = ws_size >= FAST_NEED;

    (void)hipFuncSetAttribute((const void*)k_gemm96,
                              hipFuncAttributeMaxDynamicSharedMemorySize, 147456);
    (void)hipFuncSetAttribute((const void*)k_downf,
                              hipFuncAttributeMaxDynamicSharedMemorySize, 147456);

    k_prep<<<141, 256, 0, stream>>>(down_w, down_b, ln_w, ln_b,
                                    down1_w, down1_b, ln1_w, ln1_b,
                                    wln_down, wln_down1, swcb,
                                    up_w, pw_w, wbf_up, wbf_pw, part);
    if (fast) {
        k_lnorm<<<16384, 256, 0, stream>>>(x, tt, xn, tn);
        k_gemm96<<<256, 1024, 147456, stream>>>(xn, tn, wln_down, wln_down1,
                                                swcb, x_emb, t_emb, part);
    } else {
        k_downf<<<256, 1024, 147456, stream>>>(x, tt, wln_down, wln_down1,
                                               swcb, x_emb, t_emb, part);
    }
    k_mlp<<<8, 128, 0, stream>>>(part, m1w, m1b, m2w, m2b, wts);
    k_dwconv<<<512, 256, 0, stream>>>(t_emb, dw_w, dw_b, ybuf);
    k_style<<<512, 256, 0, stream>>>(ybuf, wbf_pw, pw_b, x_emb, common);
    k_circ<<<1024, 192, 0, stream>>>(common, wts, basis, convout);
    k_up<<<2048, 256, 0, stream>>>(convout, wbf_up, up_b, x, out);
}

// Round 12
// 222.109 us; speedup vs baseline: 1.0382x; 1.0382x over previous
//
#include <hip/hip_runtime.h>

#define DIM_ 768
#define MID_ 96

typedef float f32x4 __attribute__((ext_vector_type(4)));
typedef __bf16 bf16x8 __attribute__((ext_vector_type(8)));
typedef __bf16 bf16x4 __attribute__((ext_vector_type(4)));

// ---------------------------------------------------------------------------
// K_prep: fused weight prep.
// Blocks [0,48): fold LN scale into down/down1 weights; sw/cb constants.
// Blocks [48,141): bf16-cast up_w, pw_w; zero gvec partials.
// ---------------------------------------------------------------------------
__global__ __launch_bounds__(256) void k_prep(
        const float* __restrict__ dw, const float* __restrict__ db,
        const float* __restrict__ lnw0, const float* __restrict__ lnb0,
        const float* __restrict__ d1w, const float* __restrict__ d1b,
        const float* __restrict__ lnw1, const float* __restrict__ lnb1,
        __bf16* __restrict__ wln0, __bf16* __restrict__ wln1,
        float* __restrict__ swcb,
        const float* __restrict__ uw, const float* __restrict__ pw,
        __bf16* __restrict__ bup, __bf16* __restrict__ bpw,
        float* __restrict__ part) {
    if (blockIdx.x >= 48) {
        const int t = (blockIdx.x - 48) * 256 + threadIdx.x;
        const float* src;
        __bf16* dst;
        int i;
        if (t < 18432)      { src = uw; dst = bup; i = t; }
        else if (t < 23040) { src = pw; dst = bpw; i = t - 18432; }
        else if (t < 23808) { part[t - 23040] = 0.f; return; }
        else return;
        float4 v = reinterpret_cast<const float4*>(src)[i];
        bf16x4 o;
        o[0] = (__bf16)v.x; o[1] = (__bf16)v.y;
        o[2] = (__bf16)v.z; o[3] = (__bf16)v.w;
        *reinterpret_cast<bf16x4*>(dst + (size_t)i * 4) = o;
        return;
    }
    const int wid = blockIdx.x * 4 + (threadIdx.x >> 6);
    const int lane = threadIdx.x & 63;
    const int mat = wid >= 96;
    const int n = mat ? wid - 96 : wid;
    const float* W   = mat ? d1w : dw;
    const float* bia = mat ? d1b : db;
    const float* lw  = mat ? lnw1 : lnw0;
    const float* lb  = mat ? lnb1 : lnb0;
    __bf16* dst = mat ? wln1 : wln0;
    float sacc = 0.f, cacc = 0.f;
#pragma unroll
    for (int j = 0; j < 12; ++j) {
        const int k = j * 64 + lane;
        const float w = W[(size_t)n * DIM_ + k];
        const float val = w * lw[k];
        const __bf16 bv = (__bf16)val;
        dst[(size_t)n * DIM_ + k] = bv;
        sacc += (float)bv;
        cacc += lb[k] * w;
    }
#pragma unroll
    for (int m = 1; m < 64; m <<= 1) {
        sacc += __shfl_xor(sacc, m, 64);
        cacc += __shfl_xor(cacc, m, 64);
    }
    if (lane == 0) {
        swcb[mat * 192 + n] = sacc;               // sw
        swcb[mat * 192 + 96 + n] = cacc + bia[n]; // cb
    }
}

// ---------------------------------------------------------------------------
// K_downf v4 -- strict k_up clone (the ONLY proven-fast load pattern here):
// M-tile 32, FULL K=768 staged in one burst (24 float4/thread, two 12-deep
// groups), exact fp32 LN stats per-thread during staging (thread<->row
// fixed), XOR slot swizzle (phys = slot ^ (row&7), conflict-free reads),
// ONE barrier, W streamed from L1/L2 with depth-4 named-buffer prefetch
// during MFMA. 48KB static LDS -> 3 blocks/CU, no dynamic-LDS VGPR fight.
// r9 sins fixed: 1 barrier (was 32), no W restage, no pad conflicts,
// 3 blocks/CU (was 2). Epilogue: val = acc*rstd - mu*rstd*sw + cb.
// ---------------------------------------------------------------------------
__global__ __launch_bounds__(256, 3) void k_downf(
        const float* __restrict__ xsrc, const float* __restrict__ tsrc,
        const __bf16* __restrict__ wln0, const __bf16* __restrict__ wln1,
        const float* __restrict__ swcb, __bf16* __restrict__ xemb,
        __bf16* __restrict__ temb, float* __restrict__ part) {
    __shared__ bf16x8 As[32][96];    // 48KB; [row][phys-slot], 16B slots
    __shared__ float sred[32][2];    // {rstd, mu*rstd}
    const int t = threadIdx.x;
    const int half = blockIdx.x & 1;       // 0: x, 1: t
    const int tile = blockIdx.x >> 1;      // 0..1023
    const float* src = half ? tsrc : xsrc;
    const __bf16* wln = half ? wln1 : wln0;
    const float* sc = swcb + half * 192;
    __bf16* outb = half ? temb : xemb;
    const int row0 = tile * 32;

    // ---- staging: 8 threads per row, 24 float4 each (two 12-deep bursts)
    const int srow = t >> 3;         // 0..31
    const int j8 = t & 7;
    const float* rp = src + (size_t)(row0 + srow) * DIM_ + j8 * 4;
    float s = 0.f, sq = 0.f;
#pragma unroll
    for (int h = 0; h < 2; ++h) {
        float4 v[12];
#pragma unroll
        for (int k = 0; k < 12; ++k)
            v[k] = *reinterpret_cast<const float4*>(rp + (h * 12 + k) * 32);
#pragma unroll
        for (int k = 0; k < 12; ++k) {
            const float4 w = v[k];
            s += w.x + w.y + w.z + w.w;
            sq += w.x * w.x + w.y * w.y + w.z * w.z + w.w * w.w;
            const int slot = (j8 >> 1) + (h * 12 + k) * 4;   // c4>>1
            const int phys = slot ^ (srow & 7);
            bf16x4 o;
            o[0] = (__bf16)w.x; o[1] = (__bf16)w.y;
            o[2] = (__bf16)w.z; o[3] = (__bf16)w.w;
            reinterpret_cast<bf16x4*>(&As[srow][phys])[t & 1] = o;
        }
    }
    // exact fp32 stats: reduce the 8 threads of each row
    s += __shfl_xor(s, 1, 64); sq += __shfl_xor(sq, 1, 64);
    s += __shfl_xor(s, 2, 64); sq += __shfl_xor(sq, 2, 64);
    s += __shfl_xor(s, 4, 64); sq += __shfl_xor(sq, 4, 64);
    if (j8 == 0) {
        const float mean = s * (1.f / 768.f);
        const float rstd = rsqrtf(sq * (1.f / 768.f) - mean * mean + 1e-6f);
        sred[srow][0] = rstd;
        sred[srow][1] = mean * rstd;
    }
    __syncthreads();

    // ---- MFMA: 4 waves = (mr rows-half) x (nh col-half). W streamed.
    const int lane = t & 63, wave = t >> 6;
    const int l15 = lane & 15, l4 = lane >> 4;
    const int mr = wave & 1;         // 16-row group
    const int nh = wave >> 1;        // 48-col group
    const int rowA = mr * 16 + l15;
    const __bf16* wb = wln + (size_t)(nh * 48 + l15) * DIM_ + l4 * 8;
    f32x4 acc[3] = {};

    bf16x8 b0[3], b1[3], b2[3], b3[3];
#pragma unroll
    for (int f = 0; f < 3; ++f) {
        b0[f] = *reinterpret_cast<const bf16x8*>(wb + (size_t)f * 16 * DIM_ + 0 * 32);
        b1[f] = *reinterpret_cast<const bf16x8*>(wb + (size_t)f * 16 * DIM_ + 1 * 32);
        b2[f] = *reinterpret_cast<const bf16x8*>(wb + (size_t)f * 16 * DIM_ + 2 * 32);
        b3[f] = *reinterpret_cast<const bf16x8*>(wb + (size_t)f * 16 * DIM_ + 3 * 32);
    }
    auto step = [&](bf16x8 (&b)[3], int kt, int kn) {
        const int phys = (kt * 4 + l4) ^ (rowA & 7);
        const bf16x8 a = As[rowA][phys];
#pragma unroll
        for (int f = 0; f < 3; ++f)
            acc[f] = __builtin_amdgcn_mfma_f32_16x16x32_bf16(a, b[f], acc[f], 0, 0, 0);
        if (kn < 24) {
#pragma unroll
            for (int f = 0; f < 3; ++f)
                b[f] = *reinterpret_cast<const bf16x8*>(
                    wb + (size_t)f * 16 * DIM_ + kn * 32);
        }
    };
#pragma unroll
    for (int kt = 0; kt < 24; kt += 4) {
        step(b0, kt + 0, kt + 4);
        step(b1, kt + 1, kt + 5);
        step(b2, kt + 2, kt + 6);
        step(b3, kt + 3, kt + 7);
    }

    // ---- epilogue (sred synced at the single barrier)
    const int lrow0 = mr * 16 + l4 * 4;
    float rstd_r[4], mur_r[4];
#pragma unroll
    for (int rr = 0; rr < 4; ++rr) {
        rstd_r[rr] = sred[lrow0 + rr][0];
        mur_r[rr]  = sred[lrow0 + rr][1];
    }
    const int batch = tile >> 7;     // 128 tiles per image
#pragma unroll
    for (int f = 0; f < 3; ++f) {
        const int col = nh * 48 + f * 16 + l15;
        const float swc = sc[col];
        const float cbc = sc[96 + col];
        float colsum = 0.f;
#pragma unroll
        for (int rr = 0; rr < 4; ++rr) {
            const float val = acc[f][rr] * rstd_r[rr] - mur_r[rr] * swc + cbc;
            outb[(size_t)(row0 + lrow0 + rr) * MID_ + col] = (__bf16)val;
            colsum += val;
        }
        if (half == 0) {
            colsum += __shfl_xor(colsum, 16, 64);
            colsum += __shfl_xor(colsum, 32, 64);
            if (l4 == 0) atomicAdd(&part[batch * MID_ + col], colsum);
        }
    }
}

// ---------------------------------------------------------------------------
// K_mlp: gvec mean from part, MLP (96->24 relu ->4), softmax -> wts [8,4]
// ---------------------------------------------------------------------------
__global__ __launch_bounds__(128) void k_mlp(const float* __restrict__ part,
        const float* __restrict__ m1w, const float* __restrict__ m1b,
        const float* __restrict__ m2w, const float* __restrict__ m2b,
        float* __restrict__ wts) {
    const int b = blockIdx.x, t = threadIdx.x;
    __shared__ float gv[96];
    __shared__ float hid[24];
    __shared__ float lg[4];
    if (t < 96) gv[t] = part[b * MID_ + t] * (1.f / 4096.f);
    __syncthreads();
    if (t < 24) {
        float s = m1b[t];
        for (int c = 0; c < 96; ++c) s += gv[c] * m1w[t * 96 + c];
        hid[t] = fmaxf(s, 0.f);
    }
    __syncthreads();
    if (t < 4) {
        float s = m2b[t];
        for (int j = 0; j < 24; ++j) s += hid[j] * m2w[t * 24 + j];
        lg[t] = s;
    }
    __syncthreads();
    if (t < 4) {
        const float m = fmaxf(fmaxf(lg[0], lg[1]), fmaxf(lg[2], lg[3]));
        const float e = __expf(lg[t] - m);
        const float sum = __expf(lg[0] - m) + __expf(lg[1] - m) +
                          __expf(lg[2] - m) + __expf(lg[3] - m);
        wts[b * 4 + t] = e / sum;
    }
}

// ---------------------------------------------------------------------------
// K_dwconv: depthwise 3x3 conv (zero pad) + SiLU. temb bf16 -> y bf16.
// ---------------------------------------------------------------------------
__global__ __launch_bounds__(256) void k_dwconv(const __bf16* __restrict__ temb,
        const float* __restrict__ dww, const float* __restrict__ dwb,
        __bf16* __restrict__ y) {
    __shared__ float wls[96 * 9];
    __shared__ float bls[96];
    const int t = threadIdx.x;
    for (int i = t; i < 96 * 9; i += 256) wls[i] = dww[i];
    if (t < 96) bls[t] = dwb[t];
    __syncthreads();
    const int b = blockIdx.x >> 6, h = blockIdx.x & 63;
    const __bf16* base = temb + (size_t)b * 4096 * MID_;
    for (int o = t; o < 64 * 96; o += 256) {
        const int w = o / 96;
        const int c = o - w * 96;
        float acc = bls[c];
#pragma unroll
        for (int dh = 0; dh < 3; ++dh) {
            const int hh = h + dh - 1;
            if (hh < 0 || hh > 63) continue;
#pragma unroll
            for (int dw = 0; dw < 3; ++dw) {
                const int ww = w + dw - 1;
                if (ww < 0 || ww > 63) continue;
                acc += (float)base[((size_t)hh * 64 + ww) * MID_ + c] *
                       wls[c * 9 + dh * 3 + dw];
            }
        }
        y[((size_t)(b * 64 + h) * 64 + w) * MID_ + c] =
            (__bf16)(acc / (1.f + __expf(-acc)));
    }
}

// ---------------------------------------------------------------------------
// K_style: style GEMM (y @ pw_w^T + pw_b) fused with modulation:
// common = x_emb * (1 + gamma) + beta -> bf16. K=96 fully staged, 1 barrier.
// ---------------------------------------------------------------------------
__global__ __launch_bounds__(256) void k_style(const __bf16* __restrict__ y,
        const __bf16* __restrict__ wpw, const float* __restrict__ pwb,
        const __bf16* __restrict__ xemb, __bf16* __restrict__ common) {
    __shared__ bf16x8 As[64][13];
    __shared__ bf16x8 Bs[192][13];
    const int t = threadIdx.x;
    const int row0 = blockIdx.x * 64;
    for (int idx = t; idx < 768; idx += 256) {
        const int rr = idx / 12, q = idx - rr * 12;
        As[rr][q] = *reinterpret_cast<const bf16x8*>(
            y + (size_t)(row0 + rr) * MID_ + q * 8);
    }
    for (int idx = t; idx < 2304; idx += 256) {
        const int rr = idx / 12, q = idx - rr * 12;
        Bs[rr][q] = *reinterpret_cast<const bf16x8*>(
            wpw + (size_t)rr * MID_ + q * 8);
    }
    __syncthreads();
    const int lane = t & 63, wave = t >> 6;
    const int l15 = lane & 15, l4 = lane >> 4;
    f32x4 acc[12] = {};
    const int ar = wave * 16 + l15;
#pragma unroll
    for (int kt = 0; kt < 3; ++kt) {
        bf16x8 a = As[ar][kt * 4 + l4];
#pragma unroll
        for (int f = 0; f < 12; ++f) {
            bf16x8 b = Bs[f * 16 + l15][kt * 4 + l4];
            acc[f] = __builtin_amdgcn_mfma_f32_16x16x32_bf16(a, b, acc[f], 0, 0, 0);
        }
    }
    const int orow = row0 + wave * 16 + l4 * 4;
#pragma unroll
    for (int f = 0; f < 6; ++f) {
        const int col = f * 16 + l15;
        const float pbg = pwb[col];
        const float pbb = pwb[col + 96];
#pragma unroll
        for (int rr = 0; rr < 4; ++rr) {
            const float g = acc[f][rr] + pbg;
            const float bt = acc[f + 6][rr] + pbb;
            const float xe = (float)xemb[(size_t)(orow + rr) * MID_ + col];
            common[(size_t)(orow + rr) * MID_ + col] = (__bf16)(xe * (1.f + g) + bt);
        }
    }
}

// ---------------------------------------------------------------------------
// K_circ: circular 7x7 conv (== rfft2/irfft2 product). dyn built in LDS.
// ---------------------------------------------------------------------------
__global__ __launch_bounds__(192) void k_circ(const __bf16* __restrict__ common,
        const float* __restrict__ wts, const float* __restrict__ basis,
        __bf16* __restrict__ outc) {
    __shared__ float dyn[49][96];
    const int t = threadIdx.x;
    const int b = blockIdx.x >> 7;
    const int h = (blockIdx.x >> 1) & 63;
    const int wslice = blockIdx.x & 1;
    const float w0 = wts[b * 4 + 0], w1 = wts[b * 4 + 1];
    const float w2 = wts[b * 4 + 2], w3 = wts[b * 4 + 3];
    for (int idx = t; idx < 4704; idx += 192) {
        const int c = idx / 49;
        const int pq = idx - c * 49;
        const size_t off = (size_t)c * 49 + pq;
        dyn[pq][c] = w0 * basis[off] + w1 * basis[off + 4704] +
                     w2 * basis[off + 9408] + w3 * basis[off + 14112];
    }
    __syncthreads();
    const int c = t % 96;
    const int wg = t / 96;
    const int wbase = wslice * 32 + wg * 16;
    const __bf16* cb = common + (size_t)b * 4096 * MID_ + c;
    float acc[16] = {};
#pragma unroll 1
    for (int p = 0; p < 7; ++p) {
        const int hh = (h + 3 - p) & 63;
        const __bf16* rp = cb + (size_t)hh * 64 * MID_;
        float dynr[7];
#pragma unroll
        for (int q = 0; q < 7; ++q) dynr[q] = dyn[p * 7 + q][c];
#pragma unroll
        for (int i = 0; i < 22; ++i) {
            const int ww = (wbase - 3 + i) & 63;
            const float cm = (float)rp[(size_t)ww * MID_];
#pragma unroll
            for (int q = 0; q < 7; ++q) {
                const int li = i + q - 6;
                if (li >= 0 && li < 16) acc[li] += dynr[q] * cm;
            }
        }
    }
    const size_t obase = ((size_t)(b * 64 + h) * 64 + wbase) * MID_ + c;
#pragma unroll
    for (int li = 0; li < 16; ++li)
        outc[obase + (size_t)li * MID_] = (__bf16)acc[li];
}

// ---------------------------------------------------------------------------
// K_up: out = a_in[32768,96] @ up_w_bf16[768,96]^T + up_b + x  (fp32 out)
// ---------------------------------------------------------------------------
__global__ __launch_bounds__(256) void k_up(const __bf16* __restrict__ a_in,
        const __bf16* __restrict__ wbf, const float* __restrict__ upb,
        const float* __restrict__ x, float* __restrict__ out) {
    __shared__ bf16x8 As[128][13];
    __shared__ bf16x8 Ws[96][13];
    const int t = threadIdx.x;
    const int mt = blockIdx.x >> 3, nt = blockIdx.x & 7;
    const int row0 = mt * 128, col0 = nt * 96;
    for (int idx = t; idx < 1536; idx += 256) {
        const int rr = idx / 12, q = idx - rr * 12;
        As[rr][q] = *reinterpret_cast<const bf16x8*>(
            a_in + (size_t)(row0 + rr) * MID_ + q * 8);
    }
    for (int idx = t; idx < 1152; idx += 256) {
        const int rr = idx / 12, q = idx - rr * 12;
        Ws[rr][q] = *reinterpret_cast<const bf16x8*>(
            wbf + (size_t)(col0 + rr) * MID_ + q * 8);
    }
    __syncthreads();
    const int lane = t & 63, wave = t >> 6;
    const int l15 = lane & 15, l4 = lane >> 4;
    f32x4 acc[2][6] = {};
#pragma unroll
    for (int kt = 0; kt < 3; ++kt) {
        bf16x8 a0 = As[wave * 32 + l15][kt * 4 + l4];
        bf16x8 a1 = As[wave * 32 + 16 + l15][kt * 4 + l4];
#pragma unroll
        for (int f = 0; f < 6; ++f) {
            bf16x8 b = Ws[f * 16 + l15][kt * 4 + l4];
            acc[0][f] = __builtin_amdgcn_mfma_f32_16x16x32_bf16(a0, b, acc[0][f], 0, 0, 0);
            acc[1][f] = __builtin_amdgcn_mfma_f32_16x16x32_bf16(a1, b, acc[1][f], 0, 0, 0);
        }
    }
#pragma unroll
    for (int mr = 0; mr < 2; ++mr) {
        const int orow = row0 + wave * 32 + mr * 16 + l4 * 4;
#pragma unroll
        for (int f = 0; f < 6; ++f) {
            const int col = col0 + f * 16 + l15;
            const float ub = upb[col];
#pragma unroll
            for (int rr = 0; rr < 4; ++rr) {
                const size_t idx = (size_t)(orow + rr) * DIM_ + col;
                out[idx] = acc[mr][f][rr] + ub + x[idx];
            }
        }
    }
}

// ---------------------------------------------------------------------------
extern "C" void kernel_launch(void* const* d_in, const int* in_sizes, int n_in,
                              void* d_out, int out_size, void* d_ws, size_t ws_size,
                              hipStream_t stream) {
    (void)in_sizes; (void)n_in; (void)out_size; (void)ws_size;
    const float* x      = (const float*)d_in[0];
    const float* tt     = (const float*)d_in[1];
    const float* ln_w   = (const float*)d_in[2];
    const float* ln_b   = (const float*)d_in[3];
    const float* down_w = (const float*)d_in[4];
    const float* down_b = (const float*)d_in[5];
    const float* ln1_w  = (const float*)d_in[6];
    const float* ln1_b  = (const float*)d_in[7];
    const float* down1_w= (const float*)d_in[8];
    const float* down1_b= (const float*)d_in[9];
    const float* dw_w   = (const float*)d_in[10];
    const float* dw_b   = (const float*)d_in[11];
    const float* pw_w   = (const float*)d_in[12];
    const float* pw_b   = (const float*)d_in[13];
    const float* m1w    = (const float*)d_in[14];
    const float* m1b    = (const float*)d_in[15];
    const float* m2w    = (const float*)d_in[16];
    const float* m2b    = (const float*)d_in[17];
    const float* basis  = (const float*)d_in[18];
    const float* up_w   = (const float*)d_in[19];
    const float* up_b   = (const float*)d_in[20];
    float* out = (float*)d_out;
    char* ws = (char*)d_ws;

    // workspace layout (bytes)
    __bf16* wln_down  = (__bf16*)(ws + 0);          // 96*768*2  = 147456
    __bf16* wln_down1 = (__bf16*)(ws + 147456);
    __bf16* wbf_up    = (__bf16*)(ws + 294912);     // 768*96*2
    __bf16* wbf_pw    = (__bf16*)(ws + 442368);     // 192*96*2 = 36864
    float*  part      = (float*)(ws + 479232);      // 8*96*4 = 3072
    float*  wts       = (float*)(ws + 482304);      // 32*4
    float*  swcb      = (float*)(ws + 482560);      // 2*192*4 = 1536
    __bf16* x_emb     = (__bf16*)(ws + 524288);     // 32768*96*2 = 6291456
    __bf16* t_emb     = (__bf16*)(ws + 6815744);
    __bf16* ybuf      = (__bf16*)(ws + 13107200);
    __bf16* common    = (__bf16*)(ws + 19398656);
    __bf16* convout   = (__bf16*)(ws + 25690112);

    k_prep<<<141, 256, 0, stream>>>(down_w, down_b, ln_w, ln_b,
                                    down1_w, down1_b, ln1_w, ln1_b,
                                    wln_down, wln_down1, swcb,
                                    up_w, pw_w, wbf_up, wbf_pw, part);
    k_downf<<<2048, 256, 0, stream>>>(x, tt, wln_down, wln_down1, swcb,
                                      x_emb, t_emb, part);
    k_mlp<<<8, 128, 0, stream>>>(part, m1w, m1b, m2w, m2b, wts);
    k_dwconv<<<512, 256, 0, stream>>>(t_emb, dw_w, dw_b, ybuf);
    k_style<<<512, 256, 0, stream>>>(ybuf, wbf_pw, pw_b, x_emb, common);
    k_circ<<<1024, 192, 0, stream>>>(common, wts, basis, convout);
    k_up<<<2048, 256, 0, stream>>>(convout, wbf_up, up_b, x, out);
}

// Round 13
// 186.637 us; speedup vs baseline: 1.2355x; 1.1901x over previous
//
#include <hip/hip_runtime.h>

#define DIM_ 768
#define MID_ 96

typedef float f32x4 __attribute__((ext_vector_type(4)));
typedef __bf16 bf16x8 __attribute__((ext_vector_type(8)));
typedef __bf16 bf16x4 __attribute__((ext_vector_type(4)));

// ---------------------------------------------------------------------------
// K_prep: fused weight prep.
// Blocks [0,48): fold LN scale into down/down1 weights; sw/cb constants.
// Blocks [48,141): bf16-cast up_w, pw_w; zero gvec partials.
// ---------------------------------------------------------------------------
__global__ __launch_bounds__(256) void k_prep(
        const float* __restrict__ dw, const float* __restrict__ db,
        const float* __restrict__ lnw0, const float* __restrict__ lnb0,
        const float* __restrict__ d1w, const float* __restrict__ d1b,
        const float* __restrict__ lnw1, const float* __restrict__ lnb1,
        __bf16* __restrict__ wln0, __bf16* __restrict__ wln1,
        float* __restrict__ swcb,
        const float* __restrict__ uw, const float* __restrict__ pw,
        __bf16* __restrict__ bup, __bf16* __restrict__ bpw,
        float* __restrict__ part) {
    if (blockIdx.x >= 48) {
        const int t = (blockIdx.x - 48) * 256 + threadIdx.x;
        const float* src;
        __bf16* dst;
        int i;
        if (t < 18432)      { src = uw; dst = bup; i = t; }
        else if (t < 23040) { src = pw; dst = bpw; i = t - 18432; }
        else if (t < 23808) { part[t - 23040] = 0.f; return; }
        else return;
        float4 v = reinterpret_cast<const float4*>(src)[i];
        bf16x4 o;
        o[0] = (__bf16)v.x; o[1] = (__bf16)v.y;
        o[2] = (__bf16)v.z; o[3] = (__bf16)v.w;
        *reinterpret_cast<bf16x4*>(dst + (size_t)i * 4) = o;
        return;
    }
    const int wid = blockIdx.x * 4 + (threadIdx.x >> 6);
    const int lane = threadIdx.x & 63;
    const int mat = wid >= 96;
    const int n = mat ? wid - 96 : wid;
    const float* W   = mat ? d1w : dw;
    const float* bia = mat ? d1b : db;
    const float* lw  = mat ? lnw1 : lnw0;
    const float* lb  = mat ? lnb1 : lnb0;
    __bf16* dst = mat ? wln1 : wln0;
    float sacc = 0.f, cacc = 0.f;
#pragma unroll
    for (int j = 0; j < 12; ++j) {
        const int k = j * 64 + lane;
        const float w = W[(size_t)n * DIM_ + k];
        const float val = w * lw[k];
        const __bf16 bv = (__bf16)val;
        dst[(size_t)n * DIM_ + k] = bv;
        sacc += (float)bv;
        cacc += lb[k] * w;
    }
#pragma unroll
    for (int m = 1; m < 64; m <<= 1) {
        sacc += __shfl_xor(sacc, m, 64);
        cacc += __shfl_xor(cacc, m, 64);
    }
    if (lane == 0) {
        swcb[mat * 192 + n] = sacc;               // sw
        swcb[mat * 192 + 96 + n] = cacc + bia[n]; // cb
    }
}

// ---------------------------------------------------------------------------
// K_frag: re-lay folded down-weights into MFMA fragment order in GLOBAL mem:
// wlnf[(kt*6 + f)*64 + lane] (bf16x8) = wln[(f*16 + (lane&15))*768
//                                           + kt*32 + (lane>>4)*8 .. +7]
// -> the B-operand of frag (kt,f) is one contiguous, lane-ordered 1KB block,
//    so k_downf's B loads are perfectly coalesced L2 hits. 18432 items x 2.
// ---------------------------------------------------------------------------
__global__ __launch_bounds__(256) void k_frag(
        const __bf16* __restrict__ wln0, const __bf16* __restrict__ wln1,
        __bf16* __restrict__ wf0, __bf16* __restrict__ wf1) {
    const int idx = blockIdx.x * 256 + threadIdx.x;   // 0..18431
    const int mat = idx >= 9216;
    const int i = mat ? idx - 9216 : idx;
    const __bf16* src = mat ? wln1 : wln0;
    __bf16* dst = mat ? wf1 : wf0;
    const int kt = i / 384;
    const int rem = i - kt * 384;
    const int f = rem >> 6;
    const int lane = rem & 63;
    const int row = f * 16 + (lane & 15);
    const int col = kt * 32 + (lane >> 4) * 8;
    *reinterpret_cast<bf16x8*>(dst + (size_t)i * 8) =
        *reinterpret_cast<const bf16x8*>(src + (size_t)row * DIM_ + col);
}

// ---------------------------------------------------------------------------
// K_downf v5 -- k_up-exact macro-structure (the only proven-fast pattern):
// 2048 small blocks (256 thr, 49.9KB LDS -> 3/CU resident, deep queue),
// ONE burst stage + ONE barrier + MFMA volley, then die.
// Stage: 8 thr/row, 24 float4 burst (two 12-deep groups), pack bf16x8,
// linear slot = k/8 into odd-padded As[32][97] (k_up's [13] trick; no
// hand swizzle -- r12's 4-row bank collision fixed by the odd row stride).
// Stats per-thread (fixed row) -> 3 shfl -> sred. LN algebraic epilogue.
// B: fragment-order GLOBAL W (k_frag), 1KB coalesced L2-hit loads,
// depth-3 named rotation overlapping MFMA.
// ---------------------------------------------------------------------------
__global__ __launch_bounds__(256, 3) void k_downf(
        const float* __restrict__ xsrc, const float* __restrict__ tsrc,
        const __bf16* __restrict__ wf0, const __bf16* __restrict__ wf1,
        const float* __restrict__ swcb, __bf16* __restrict__ xemb,
        __bf16* __restrict__ temb, float* __restrict__ part) {
    __shared__ bf16x8 As[32][97];    // odd pad: row stride 1552B == 4 banks
    __shared__ float sred[32][2];    // {rstd, mu*rstd}
    const int t = threadIdx.x;
    const int half = blockIdx.x & 1;       // 0: x, 1: t
    const int tile = blockIdx.x >> 1;      // 0..1023
    const float* src = half ? tsrc : xsrc;
    const __bf16* wf = half ? wf1 : wf0;
    const float* sc = swcb + half * 192;
    __bf16* outb = half ? temb : xemb;
    const int row0 = tile * 32;

    // ---- stage: thread (row=t>>3, j8=t&7) covers floats j8*8 + kk*64
    const int srow = t >> 3, j8 = t & 7;
    const float* rp = src + (size_t)(row0 + srow) * DIM_ + j8 * 8;
    float s = 0.f, sq = 0.f;
#pragma unroll
    for (int h = 0; h < 2; ++h) {
        float4 v0[6], v1[6];
#pragma unroll
        for (int k = 0; k < 6; ++k) {
            const int kk = h * 6 + k;
            v0[k] = *reinterpret_cast<const float4*>(rp + kk * 64);
            v1[k] = *reinterpret_cast<const float4*>(rp + kk * 64 + 4);
        }
#pragma unroll
        for (int k = 0; k < 6; ++k) {
            const int kk = h * 6 + k;
            const float4 a = v0[k], b = v1[k];
            s += a.x + a.y + a.z + a.w + b.x + b.y + b.z + b.w;
            sq += a.x * a.x + a.y * a.y + a.z * a.z + a.w * a.w +
                  b.x * b.x + b.y * b.y + b.z * b.z + b.w * b.w;
            bf16x8 o;
            o[0] = (__bf16)a.x; o[1] = (__bf16)a.y;
            o[2] = (__bf16)a.z; o[3] = (__bf16)a.w;
            o[4] = (__bf16)b.x; o[5] = (__bf16)b.y;
            o[6] = (__bf16)b.z; o[7] = (__bf16)b.w;
            As[srow][kk * 8 + j8] = o;   // slot == k/8, linear
        }
    }
    // exact fp32 stats: combine the 8 threads of each row
    s += __shfl_xor(s, 1, 64); sq += __shfl_xor(sq, 1, 64);
    s += __shfl_xor(s, 2, 64); sq += __shfl_xor(sq, 2, 64);
    s += __shfl_xor(s, 4, 64); sq += __shfl_xor(sq, 4, 64);
    if (j8 == 0) {
        const float mean = s * (1.f / 768.f);
        const float rstd = rsqrtf(sq * (1.f / 768.f) - mean * mean + 1e-6f);
        sred[srow][0] = rstd;
        sred[srow][1] = mean * rstd;
    }
    __syncthreads();

    // ---- MFMA: 4 waves = (mr row-half) x (nh col-half)
    const int lane = t & 63, wave = t >> 6;
    const int l15 = lane & 15, l4 = lane >> 4;
    const int mr = wave & 1;          // 16-row group
    const int nh = wave >> 1;         // 48-col group
    const int rowA = mr * 16 + l15;
    // B frag (kt, fg=nh*3+f) at wf + ((kt*6+fg)*64 + lane)*8
    const __bf16* wfb = wf + ((size_t)nh * 3 * 64 + lane) * 8;
    f32x4 acc[3] = {};
    bf16x8 b0[3], b1[3], b2[3];
#pragma unroll
    for (int f = 0; f < 3; ++f) {
        b0[f] = *reinterpret_cast<const bf16x8*>(wfb + (size_t)(0 * 6 + f) * 512);
        b1[f] = *reinterpret_cast<const bf16x8*>(wfb + (size_t)(1 * 6 + f) * 512);
        b2[f] = *reinterpret_cast<const bf16x8*>(wfb + (size_t)(2 * 6 + f) * 512);
    }
    auto step = [&](bf16x8 (&bb)[3], int kt, int kn) {
        const bf16x8 a = As[rowA][kt * 4 + l4];
#pragma unroll
        for (int f = 0; f < 3; ++f)
            acc[f] = __builtin_amdgcn_mfma_f32_16x16x32_bf16(a, bb[f], acc[f], 0, 0, 0);
        if (kn < 24) {
#pragma unroll
            for (int f = 0; f < 3; ++f)
                bb[f] = *reinterpret_cast<const bf16x8*>(
                    wfb + ((size_t)kn * 6 + f) * 512);
        }
    };
#pragma unroll
    for (int kt = 0; kt < 24; kt += 3) {
        step(b0, kt + 0, kt + 3);
        step(b1, kt + 1, kt + 4);
        step(b2, kt + 2, kt + 5);
    }

    // ---- epilogue
    const int lrow0 = mr * 16 + l4 * 4;
    float rstd_r[4], mur_r[4];
#pragma unroll
    for (int rr = 0; rr < 4; ++rr) {
        rstd_r[rr] = sred[lrow0 + rr][0];
        mur_r[rr]  = sred[lrow0 + rr][1];
    }
    const int batch = tile >> 7;     // 128 tiles per image
#pragma unroll
    for (int f = 0; f < 3; ++f) {
        const int col = nh * 48 + f * 16 + l15;
        const float swc = sc[col];
        const float cbc = sc[96 + col];
        float colsum = 0.f;
#pragma unroll
        for (int rr = 0; rr < 4; ++rr) {
            const float val = acc[f][rr] * rstd_r[rr] - mur_r[rr] * swc + cbc;
            outb[(size_t)(row0 + lrow0 + rr) * MID_ + col] = (__bf16)val;
            colsum += val;
        }
        if (half == 0) {
            colsum += __shfl_xor(colsum, 16, 64);
            colsum += __shfl_xor(colsum, 32, 64);
            if (l4 == 0) atomicAdd(&part[batch * MID_ + col], colsum);
        }
    }
}

// ---------------------------------------------------------------------------
// K_mlp: gvec mean from part, MLP (96->24 relu ->4), softmax -> wts [8,4]
// ---------------------------------------------------------------------------
__global__ __launch_bounds__(128) void k_mlp(const float* __restrict__ part,
        const float* __restrict__ m1w, const float* __restrict__ m1b,
        const float* __restrict__ m2w, const float* __restrict__ m2b,
        float* __restrict__ wts) {
    const int b = blockIdx.x, t = threadIdx.x;
    __shared__ float gv[96];
    __shared__ float hid[24];
    __shared__ float lg[4];
    if (t < 96) gv[t] = part[b * MID_ + t] * (1.f / 4096.f);
    __syncthreads();
    if (t < 24) {
        float s = m1b[t];
        for (int c = 0; c < 96; ++c) s += gv[c] * m1w[t * 96 + c];
        hid[t] = fmaxf(s, 0.f);
    }
    __syncthreads();
    if (t < 4) {
        float s = m2b[t];
        for (int j = 0; j < 24; ++j) s += hid[j] * m2w[t * 24 + j];
        lg[t] = s;
    }
    __syncthreads();
    if (t < 4) {
        const float m = fmaxf(fmaxf(lg[0], lg[1]), fmaxf(lg[2], lg[3]));
        const float e = __expf(lg[t] - m);
        const float sum = __expf(lg[0] - m) + __expf(lg[1] - m) +
                          __expf(lg[2] - m) + __expf(lg[3] - m);
        wts[b * 4 + t] = e / sum;
    }
}

// ---------------------------------------------------------------------------
// K_dwconv: depthwise 3x3 conv (zero pad) + SiLU. temb bf16 -> y bf16.
// ---------------------------------------------------------------------------
__global__ __launch_bounds__(256) void k_dwconv(const __bf16* __restrict__ temb,
        const float* __restrict__ dww, const float* __restrict__ dwb,
        __bf16* __restrict__ y) {
    __shared__ float wls[96 * 9];
    __shared__ float bls[96];
    const int t = threadIdx.x;
    for (int i = t; i < 96 * 9; i += 256) wls[i] = dww[i];
    if (t < 96) bls[t] = dwb[t];
    __syncthreads();
    const int b = blockIdx.x >> 6, h = blockIdx.x & 63;
    const __bf16* base = temb + (size_t)b * 4096 * MID_;
    for (int o = t; o < 64 * 96; o += 256) {
        const int w = o / 96;
        const int c = o - w * 96;
        float acc = bls[c];
#pragma unroll
        for (int dh = 0; dh < 3; ++dh) {
            const int hh = h + dh - 1;
            if (hh < 0 || hh > 63) continue;
#pragma unroll
            for (int dw = 0; dw < 3; ++dw) {
                const int ww = w + dw - 1;
                if (ww < 0 || ww > 63) continue;
                acc += (float)base[((size_t)hh * 64 + ww) * MID_ + c] *
                       wls[c * 9 + dh * 3 + dw];
            }
        }
        y[((size_t)(b * 64 + h) * 64 + w) * MID_ + c] =
            (__bf16)(acc / (1.f + __expf(-acc)));
    }
}

// ---------------------------------------------------------------------------
// K_style: style GEMM (y @ pw_w^T + pw_b) fused with modulation:
// common = x_emb * (1 + gamma) + beta -> bf16. K=96 fully staged, 1 barrier.
// ---------------------------------------------------------------------------
__global__ __launch_bounds__(256) void k_style(const __bf16* __restrict__ y,
        const __bf16* __restrict__ wpw, const float* __restrict__ pwb,
        const __bf16* __restrict__ xemb, __bf16* __restrict__ common) {
    __shared__ bf16x8 As[64][13];
    __shared__ bf16x8 Bs[192][13];
    const int t = threadIdx.x;
    const int row0 = blockIdx.x * 64;
    for (int idx = t; idx < 768; idx += 256) {
        const int rr = idx / 12, q = idx - rr * 12;
        As[rr][q] = *reinterpret_cast<const bf16x8*>(
            y + (size_t)(row0 + rr) * MID_ + q * 8);
    }
    for (int idx = t; idx < 2304; idx += 256) {
        const int rr = idx / 12, q = idx - rr * 12;
        Bs[rr][q] = *reinterpret_cast<const bf16x8*>(
            wpw + (size_t)rr * MID_ + q * 8);
    }
    __syncthreads();
    const int lane = t & 63, wave = t >> 6;
    const int l15 = lane & 15, l4 = lane >> 4;
    f32x4 acc[12] = {};
    const int ar = wave * 16 + l15;
#pragma unroll
    for (int kt = 0; kt < 3; ++kt) {
        bf16x8 a = As[ar][kt * 4 + l4];
#pragma unroll
        for (int f = 0; f < 12; ++f) {
            bf16x8 b = Bs[f * 16 + l15][kt * 4 + l4];
            acc[f] = __builtin_amdgcn_mfma_f32_16x16x32_bf16(a, b, acc[f], 0, 0, 0);
        }
    }
    const int orow = row0 + wave * 16 + l4 * 4;
#pragma unroll
    for (int f = 0; f < 6; ++f) {
        const int col = f * 16 + l15;
        const float pbg = pwb[col];
        const float pbb = pwb[col + 96];
#pragma unroll
        for (int rr = 0; rr < 4; ++rr) {
            const float g = acc[f][rr] + pbg;
            const float bt = acc[f + 6][rr] + pbb;
            const float xe = (float)xemb[(size_t)(orow + rr) * MID_ + col];
            common[(size_t)(orow + rr) * MID_ + col] = (__bf16)(xe * (1.f + g) + bt);
        }
    }
}

// ---------------------------------------------------------------------------
// K_circ: circular 7x7 conv (== rfft2/irfft2 product). dyn built in LDS.
// ---------------------------------------------------------------------------
__global__ __launch_bounds__(192) void k_circ(const __bf16* __restrict__ common,
        const float* __restrict__ wts, const float* __restrict__ basis,
        __bf16* __restrict__ outc) {
    __shared__ float dyn[49][96];
    const int t = threadIdx.x;
    const int b = blockIdx.x >> 7;
    const int h = (blockIdx.x >> 1) & 63;
    const int wslice = blockIdx.x & 1;
    const float w0 = wts[b * 4 + 0], w1 = wts[b * 4 + 1];
    const float w2 = wts[b * 4 + 2], w3 = wts[b * 4 + 3];
    for (int idx = t; idx < 4704; idx += 192) {
        const int c = idx / 49;
        const int pq = idx - c * 49;
        const size_t off = (size_t)c * 49 + pq;
        dyn[pq][c] = w0 * basis[off] + w1 * basis[off + 4704] +
                     w2 * basis[off + 9408] + w3 * basis[off + 14112];
    }
    __syncthreads();
    const int c = t % 96;
    const int wg = t / 96;
    const int wbase = wslice * 32 + wg * 16;
    const __bf16* cb = common + (size_t)b * 4096 * MID_ + c;
    float acc[16] = {};
#pragma unroll 1
    for (int p = 0; p < 7; ++p) {
        const int hh = (h + 3 - p) & 63;
        const __bf16* rp = cb + (size_t)hh * 64 * MID_;
        float dynr[7];
#pragma unroll
        for (int q = 0; q < 7; ++q) dynr[q] = dyn[p * 7 + q][c];
#pragma unroll
        for (int i = 0; i < 22; ++i) {
            const int ww = (wbase - 3 + i) & 63;
            const float cm = (float)rp[(size_t)ww * MID_];
#pragma unroll
            for (int q = 0; q < 7; ++q) {
                const int li = i + q - 6;
                if (li >= 0 && li < 16) acc[li] += dynr[q] * cm;
            }
        }
    }
    const size_t obase = ((size_t)(b * 64 + h) * 64 + wbase) * MID_ + c;
#pragma unroll
    for (int li = 0; li < 16; ++li)
        outc[obase + (size_t)li * MID_] = (__bf16)acc[li];
}

// ---------------------------------------------------------------------------
// K_up: out = a_in[32768,96] @ up_w_bf16[768,96]^T + up_b + x  (fp32 out)
// ---------------------------------------------------------------------------
__global__ __launch_bounds__(256) void k_up(const __bf16* __restrict__ a_in,
        const __bf16* __restrict__ wbf, const float* __restrict__ upb,
        const float* __restrict__ x, float* __restrict__ out) {
    __shared__ bf16x8 As[128][13];
    __shared__ bf16x8 Ws[96][13];
    const int t = threadIdx.x;
    const int mt = blockIdx.x >> 3, nt = blockIdx.x & 7;
    const int row0 = mt * 128, col0 = nt * 96;
    for (int idx = t; idx < 1536; idx += 256) {
        const int rr = idx / 12, q = idx - rr * 12;
        As[rr][q] = *reinterpret_cast<const bf16x8*>(
            a_in + (size_t)(row0 + rr) * MID_ + q * 8);
    }
    for (int idx = t; idx < 1152; idx += 256) {
        const int rr = idx / 12, q = idx - rr * 12;
        Ws[rr][q] = *reinterpret_cast<const bf16x8*>(
            wbf + (size_t)(col0 + rr) * MID_ + q * 8);
    }
    __syncthreads();
    const int lane = t & 63, wave = t >> 6;
    const int l15 = lane & 15, l4 = lane >> 4;
    f32x4 acc[2][6] = {};
#pragma unroll
    for (int kt = 0; kt < 3; ++kt) {
        bf16x8 a0 = As[wave * 32 + l15][kt * 4 + l4];
        bf16x8 a1 = As[wave * 32 + 16 + l15][kt * 4 + l4];
#pragma unroll
        for (int f = 0; f < 6; ++f) {
            bf16x8 b = Ws[f * 16 + l15][kt * 4 + l4];
            acc[0][f] = __builtin_amdgcn_mfma_f32_16x16x32_bf16(a0, b, acc[0][f], 0, 0, 0);
            acc[1][f] = __builtin_amdgcn_mfma_f32_16x16x32_bf16(a1, b, acc[1][f], 0, 0, 0);
        }
    }
#pragma unroll
    for (int mr = 0; mr < 2; ++mr) {
        const int orow = row0 + wave * 32 + mr * 16 + l4 * 4;
#pragma unroll
        for (int f = 0; f < 6; ++f) {
            const int col = col0 + f * 16 + l15;
            const float ub = upb[col];
#pragma unroll
            for (int rr = 0; rr < 4; ++rr) {
                const size_t idx = (size_t)(orow + rr) * DIM_ + col;
                out[idx] = acc[mr][f][rr] + ub + x[idx];
            }
        }
    }
}

// ---------------------------------------------------------------------------
extern "C" void kernel_launch(void* const* d_in, const int* in_sizes, int n_in,
                              void* d_out, int out_size, void* d_ws, size_t ws_size,
                              hipStream_t stream) {
    (void)in_sizes; (void)n_in; (void)out_size; (void)ws_size;
    const float* x      = (const float*)d_in[0];
    const float* tt     = (const float*)d_in[1];
    const float* ln_w   = (const float*)d_in[2];
    const float* ln_b   = (const float*)d_in[3];
    const float* down_w = (const float*)d_in[4];
    const float* down_b = (const float*)d_in[5];
    const float* ln1_w  = (const float*)d_in[6];
    const float* ln1_b  = (const float*)d_in[7];
    const float* down1_w= (const float*)d_in[8];
    const float* down1_b= (const float*)d_in[9];
    const float* dw_w   = (const float*)d_in[10];
    const float* dw_b   = (const float*)d_in[11];
    const float* pw_w   = (const float*)d_in[12];
    const float* pw_b   = (const float*)d_in[13];
    const float* m1w    = (const float*)d_in[14];
    const float* m1b    = (const float*)d_in[15];
    const float* m2w    = (const float*)d_in[16];
    const float* m2b    = (const float*)d_in[17];
    const float* basis  = (const float*)d_in[18];
    const float* up_w   = (const float*)d_in[19];
    const float* up_b   = (const float*)d_in[20];
    float* out = (float*)d_out;
    char* ws = (char*)d_ws;

    // workspace layout (bytes)
    __bf16* wln_down  = (__bf16*)(ws + 0);          // 96*768*2  = 147456
    __bf16* wln_down1 = (__bf16*)(ws + 147456);
    __bf16* wbf_up    = (__bf16*)(ws + 294912);     // 768*96*2
    __bf16* wbf_pw    = (__bf16*)(ws + 442368);     // 192*96*2 = 36864
    float*  part      = (float*)(ws + 479232);      // 8*96*4 = 3072
    float*  wts       = (float*)(ws + 482304);      // 32*4
    float*  swcb      = (float*)(ws + 482560);      // 2*192*4 = 1536
    __bf16* x_emb     = (__bf16*)(ws + 524288);     // 32768*96*2 = 6291456
    __bf16* t_emb     = (__bf16*)(ws + 6815744);
    __bf16* ybuf      = (__bf16*)(ws + 13107200);
    __bf16* common    = (__bf16*)(ws + 19398656);
    __bf16* convout   = (__bf16*)(ws + 25690112);
    __bf16* wf0       = (__bf16*)(ws + 31981568);   // 147456 (fragment order)
    __bf16* wf1       = (__bf16*)(ws + 32129024);   // 147456

    k_prep<<<141, 256, 0, stream>>>(down_w, down_b, ln_w, ln_b,
                                    down1_w, down1_b, ln1_w, ln1_b,
                                    wln_down, wln_down1, swcb,
                                    up_w, pw_w, wbf_up, wbf_pw, part);
    k_frag<<<72, 256, 0, stream>>>(wln_down, wln_down1, wf0, wf1);
    k_downf<<<2048, 256, 0, stream>>>(x, tt, wf0, wf1, swcb,
                                      x_emb, t_emb, part);
    k_mlp<<<8, 128, 0, stream>>>(part, m1w, m1b, m2w, m2b, wts);
    k_dwconv<<<512, 256, 0, stream>>>(t_emb, dw_w, dw_b, ybuf);
    k_style<<<512, 256, 0, stream>>>(ybuf, wbf_pw, pw_b, x_emb, common);
    k_circ<<<1024, 192, 0, stream>>>(common, wts, basis, convout);
    k_up<<<2048, 256, 0, stream>>>(convout, wbf_up, up_b, x, out);
}

// Round 14
// 174.039 us; speedup vs baseline: 1.3250x; 1.0724x over previous
//
#include <hip/hip_runtime.h>

#define DIM_ 768
#define MID_ 96

typedef float f32x4 __attribute__((ext_vector_type(4)));
typedef __bf16 bf16x8 __attribute__((ext_vector_type(8)));
typedef __bf16 bf16x4 __attribute__((ext_vector_type(4)));

// ---------------------------------------------------------------------------
// K_prep: fused weight prep.
// Blocks [0,48): fold LN scale into down/down1 weights; sw/cb constants.
// Blocks [48,141): bf16-cast up_w, pw_w; zero gvec partials.
// ---------------------------------------------------------------------------
__global__ __launch_bounds__(256) void k_prep(
        const float* __restrict__ dw, const float* __restrict__ db,
        const float* __restrict__ lnw0, const float* __restrict__ lnb0,
        const float* __restrict__ d1w, const float* __restrict__ d1b,
        const float* __restrict__ lnw1, const float* __restrict__ lnb1,
        __bf16* __restrict__ wln0, __bf16* __restrict__ wln1,
        float* __restrict__ swcb,
        const float* __restrict__ uw, const float* __restrict__ pw,
        __bf16* __restrict__ bup, __bf16* __restrict__ bpw,
        float* __restrict__ part) {
    if (blockIdx.x >= 48) {
        const int t = (blockIdx.x - 48) * 256 + threadIdx.x;
        const float* src;
        __bf16* dst;
        int i;
        if (t < 18432)      { src = uw; dst = bup; i = t; }
        else if (t < 23040) { src = pw; dst = bpw; i = t - 18432; }
        else if (t < 23808) { part[t - 23040] = 0.f; return; }
        else return;
        float4 v = reinterpret_cast<const float4*>(src)[i];
        bf16x4 o;
        o[0] = (__bf16)v.x; o[1] = (__bf16)v.y;
        o[2] = (__bf16)v.z; o[3] = (__bf16)v.w;
        *reinterpret_cast<bf16x4*>(dst + (size_t)i * 4) = o;
        return;
    }
    const int wid = blockIdx.x * 4 + (threadIdx.x >> 6);
    const int lane = threadIdx.x & 63;
    const int mat = wid >= 96;
    const int n = mat ? wid - 96 : wid;
    const float* W   = mat ? d1w : dw;
    const float* bia = mat ? d1b : db;
    const float* lw  = mat ? lnw1 : lnw0;
    const float* lb  = mat ? lnb1 : lnb0;
    __bf16* dst = mat ? wln1 : wln0;
    float sacc = 0.f, cacc = 0.f;
#pragma unroll
    for (int j = 0; j < 12; ++j) {
        const int k = j * 64 + lane;
        const float w = W[(size_t)n * DIM_ + k];
        const float val = w * lw[k];
        const __bf16 bv = (__bf16)val;
        dst[(size_t)n * DIM_ + k] = bv;
        sacc += (float)bv;
        cacc += lb[k] * w;
    }
#pragma unroll
    for (int m = 1; m < 64; m <<= 1) {
        sacc += __shfl_xor(sacc, m, 64);
        cacc += __shfl_xor(cacc, m, 64);
    }
    if (lane == 0) {
        swcb[mat * 192 + n] = sacc;               // sw
        swcb[mat * 192 + 96 + n] = cacc + bia[n]; // cb
    }
}

// ---------------------------------------------------------------------------
// K_downf: r8 version (best of 11 down-path variants, 91 us).
// Fused LN+GEMM for BOTH x and t. Grid 256: blocks [0,128) x, [128,256) t.
// 1024 thr (16 waves), 256 rows; each wave 16 rows x full N=96.
// W (96x768 bf16 = 147 KB) LDS-resident in fragment order (conflict-free).
// bf16 pipeline to fit 64 VGPR (no spill); stats folded into convert.
// LN algebraic: out = acc*rstd - mu*rstd*sw + cb.
// ---------------------------------------------------------------------------
__global__ __launch_bounds__(1024)
__attribute__((amdgpu_waves_per_eu(4, 4)))
void k_downf(
        const float* __restrict__ xsrc, const float* __restrict__ tsrc,
        const __bf16* __restrict__ wln0, const __bf16* __restrict__ wln1,
        const float* __restrict__ swcb, __bf16* __restrict__ xemb,
        __bf16* __restrict__ temb, float* __restrict__ part) {
    extern __shared__ __bf16 Wp[];   // 96*768 = 73728 elems = 147456 B
    const int t = threadIdx.x;
    const int half = blockIdx.x >> 7;      // 0: x, 1: t
    const int mb = blockIdx.x & 127;
    const float* src = half ? tsrc : xsrc;
    const __bf16* wln = half ? wln1 : wln0;
    const float* sc = swcb + half * 192;
    __bf16* outb = half ? temb : xemb;

    // stage W in fragment order: idx = (kt*6 + f)*64 + lane
#pragma unroll
    for (int i = 0; i < 9; ++i) {
        const int idx = t + i * 1024;          // 0..9215
        const int ls = idx & 63;
        const int rem = idx >> 6;              // kt*6 + f
        const int kt = rem / 6;
        const int f = rem - kt * 6;
        const int row = f * 16 + (ls & 15);
        const int col = kt * 32 + (ls >> 4) * 8;
        *reinterpret_cast<bf16x8*>(Wp + (size_t)idx * 8) =
            *reinterpret_cast<const bf16x8*>(wln + (size_t)row * DIM_ + col);
    }
    __syncthreads();

    const int lane = t & 63, wave = t >> 6;   // 16 waves
    const int l15 = lane & 15, l4 = lane >> 4;
    const int row = mb * 256 + wave * 16 + l15;
    const float* rp = src + (size_t)row * DIM_ + l4 * 8;

    float s = 0.f, sq = 0.f;
    f32x4 acc[6] = {};

    auto cvt = [&](const float4& v0, const float4& v1) -> bf16x8 {
        s += v0.x + v0.y + v0.z + v0.w + v1.x + v1.y + v1.z + v1.w;
        sq += v0.x * v0.x + v0.y * v0.y + v0.z * v0.z + v0.w * v0.w +
              v1.x * v1.x + v1.y * v1.y + v1.z * v1.z + v1.w * v1.w;
        bf16x8 a;
        a[0] = (__bf16)v0.x; a[1] = (__bf16)v0.y;
        a[2] = (__bf16)v0.z; a[3] = (__bf16)v0.w;
        a[4] = (__bf16)v1.x; a[5] = (__bf16)v1.y;
        a[6] = (__bf16)v1.z; a[7] = (__bf16)v1.w;
        return a;
    };
    auto consume = [&](const bf16x8& a, int kt) {
        const __bf16* bp = Wp + ((size_t)(kt * 6) * 64 + lane) * 8;
#pragma unroll
        for (int f = 0; f < 6; ++f) {
            bf16x8 b = *reinterpret_cast<const bf16x8*>(bp + (size_t)f * 64 * 8);
            acc[f] = __builtin_amdgcn_mfma_f32_16x16x32_bf16(a, b, acc[f], 0, 0, 0);
        }
    };

    float4 w0a = *reinterpret_cast<const float4*>(rp + 0);
    float4 w0b = *reinterpret_cast<const float4*>(rp + 4);
    float4 w1a = *reinterpret_cast<const float4*>(rp + 32);
    float4 w1b = *reinterpret_cast<const float4*>(rp + 36);
    bf16x8 a0 = cvt(w0a, w0b);
    bf16x8 a1 = cvt(w1a, w1b);
    w0a = *reinterpret_cast<const float4*>(rp + 64);
    w0b = *reinterpret_cast<const float4*>(rp + 68);
    w1a = *reinterpret_cast<const float4*>(rp + 96);
    w1b = *reinterpret_cast<const float4*>(rp + 100);
#pragma unroll
    for (int kt = 0; kt < 24; kt += 2) {
        consume(a0, kt);
        if (kt + 2 < 24) {
            a0 = cvt(w0a, w0b);
            if (kt + 4 < 24) {
                w0a = *reinterpret_cast<const float4*>(rp + (kt + 4) * 32);
                w0b = *reinterpret_cast<const float4*>(rp + (kt + 4) * 32 + 4);
            }
        }
        consume(a1, kt + 1);
        if (kt + 3 < 24) {
            a1 = cvt(w1a, w1b);
            if (kt + 5 < 24) {
                w1a = *reinterpret_cast<const float4*>(rp + (kt + 5) * 32);
                w1b = *reinterpret_cast<const float4*>(rp + (kt + 5) * 32 + 4);
            }
        }
    }

    s += __shfl_xor(s, 16, 64); sq += __shfl_xor(sq, 16, 64);
    s += __shfl_xor(s, 32, 64); sq += __shfl_xor(sq, 32, 64);
    const float mean = s * (1.f / 768.f);
    const float rstd = rsqrtf(sq * (1.f / 768.f) - mean * mean + 1e-6f);
    const float mur = mean * rstd;
    float rstd_r[4], mur_r[4];
#pragma unroll
    for (int rr = 0; rr < 4; ++rr) {
        rstd_r[rr] = __shfl(rstd, l4 * 4 + rr, 64);
        mur_r[rr]  = __shfl(mur,  l4 * 4 + rr, 64);
    }

    const int orow0 = mb * 256 + wave * 16 + l4 * 4;
    const int batch = mb >> 4;     // 16 blocks per image
#pragma unroll
    for (int f = 0; f < 6; ++f) {
        const int col = f * 16 + l15;
        const float swc = sc[col];
        const float cbc = sc[96 + col];
        float colsum = 0.f;
#pragma unroll
        for (int rr = 0; rr < 4; ++rr) {
            const float val = acc[f][rr] * rstd_r[rr] - mur_r[rr] * swc + cbc;
            outb[(size_t)(orow0 + rr) * MID_ + col] = (__bf16)val;
            colsum += val;
        }
        if (half == 0) {
            colsum += __shfl_xor(colsum, 16, 64);
            colsum += __shfl_xor(colsum, 32, 64);
            if (l4 == 0) atomicAdd(&part[batch * MID_ + col], colsum);
        }
    }
}

// ---------------------------------------------------------------------------
// K_mlp: gvec mean from part, MLP (96->24 relu ->4), softmax -> wts [8,4]
// ---------------------------------------------------------------------------
__global__ __launch_bounds__(128) void k_mlp(const float* __restrict__ part,
        const float* __restrict__ m1w, const float* __restrict__ m1b,
        const float* __restrict__ m2w, const float* __restrict__ m2b,
        float* __restrict__ wts) {
    const int b = blockIdx.x, t = threadIdx.x;
    __shared__ float gv[96];
    __shared__ float hid[24];
    __shared__ float lg[4];
    if (t < 96) gv[t] = part[b * MID_ + t] * (1.f / 4096.f);
    __syncthreads();
    if (t < 24) {
        float s = m1b[t];
        for (int c = 0; c < 96; ++c) s += gv[c] * m1w[t * 96 + c];
        hid[t] = fmaxf(s, 0.f);
    }
    __syncthreads();
    if (t < 4) {
        float s = m2b[t];
        for (int j = 0; j < 24; ++j) s += hid[j] * m2w[t * 24 + j];
        lg[t] = s;
    }
    __syncthreads();
    if (t < 4) {
        const float m = fmaxf(fmaxf(lg[0], lg[1]), fmaxf(lg[2], lg[3]));
        const float e = __expf(lg[t] - m);
        const float sum = __expf(lg[0] - m) + __expf(lg[1] - m) +
                          __expf(lg[2] - m) + __expf(lg[3] - m);
        wts[b * 4 + t] = e / sum;
    }
}

// ---------------------------------------------------------------------------
// K_dyn: precompute dyn kernels once per batch: dyng[b][pq][c] =
// sum_k wts[b][k] * basis[k][c][pq].  (removes 1024 redundant per-block
// rebuilds from k_circ).  37632 elems, coalesced writes.
// ---------------------------------------------------------------------------
__global__ __launch_bounds__(256) void k_dyn(const float* __restrict__ wts,
        const float* __restrict__ basis, float* __restrict__ dyng) {
    const int idx = blockIdx.x * 256 + threadIdx.x;
    if (idx >= 8 * 4704) return;
    const int b = idx / 4704;
    const int rem = idx - b * 4704;     // pq*96 + c
    const int pq = rem / 96;
    const int c = rem - pq * 96;
    const size_t off = (size_t)c * 49 + pq;
    dyng[idx] = wts[b * 4 + 0] * basis[off] +
                wts[b * 4 + 1] * basis[off + 4704] +
                wts[b * 4 + 2] * basis[off + 9408] +
                wts[b * 4 + 3] * basis[off + 14112];
}

// ---------------------------------------------------------------------------
// K_dwconv: depthwise 3x3 conv (zero pad) + SiLU. temb bf16 -> y bf16.
// ---------------------------------------------------------------------------
__global__ __launch_bounds__(256) void k_dwconv(const __bf16* __restrict__ temb,
        const float* __restrict__ dww, const float* __restrict__ dwb,
        __bf16* __restrict__ y) {
    __shared__ float wls[96 * 9];
    __shared__ float bls[96];
    const int t = threadIdx.x;
    for (int i = t; i < 96 * 9; i += 256) wls[i] = dww[i];
    if (t < 96) bls[t] = dwb[t];
    __syncthreads();
    const int b = blockIdx.x >> 6, h = blockIdx.x & 63;
    const __bf16* base = temb + (size_t)b * 4096 * MID_;
    for (int o = t; o < 64 * 96; o += 256) {
        const int w = o / 96;
        const int c = o - w * 96;
        float acc = bls[c];
#pragma unroll
        for (int dh = 0; dh < 3; ++dh) {
            const int hh = h + dh - 1;
            if (hh < 0 || hh > 63) continue;
#pragma unroll
            for (int dw = 0; dw < 3; ++dw) {
                const int ww = w + dw - 1;
                if (ww < 0 || ww > 63) continue;
                acc += (float)base[((size_t)hh * 64 + ww) * MID_ + c] *
                       wls[c * 9 + dh * 3 + dw];
            }
        }
        y[((size_t)(b * 64 + h) * 64 + w) * MID_ + c] =
            (__bf16)(acc / (1.f + __expf(-acc)));
    }
}

// ---------------------------------------------------------------------------
// K_style: style GEMM (y @ pw_w^T + pw_b) fused with modulation:
// common = x_emb * (1 + gamma) + beta -> bf16. K=96 fully staged, 1 barrier.
// ---------------------------------------------------------------------------
__global__ __launch_bounds__(256) void k_style(const __bf16* __restrict__ y,
        const __bf16* __restrict__ wpw, const float* __restrict__ pwb,
        const __bf16* __restrict__ xemb, __bf16* __restrict__ common) {
    __shared__ bf16x8 As[64][13];
    __shared__ bf16x8 Bs[192][13];
    const int t = threadIdx.x;
    const int row0 = blockIdx.x * 64;
    for (int idx = t; idx < 768; idx += 256) {
        const int rr = idx / 12, q = idx - rr * 12;
        As[rr][q] = *reinterpret_cast<const bf16x8*>(
            y + (size_t)(row0 + rr) * MID_ + q * 8);
    }
    for (int idx = t; idx < 2304; idx += 256) {
        const int rr = idx / 12, q = idx - rr * 12;
        Bs[rr][q] = *reinterpret_cast<const bf16x8*>(
            wpw + (size_t)rr * MID_ + q * 8);
    }
    __syncthreads();
    const int lane = t & 63, wave = t >> 6;
    const int l15 = lane & 15, l4 = lane >> 4;
    f32x4 acc[12] = {};
    const int ar = wave * 16 + l15;
#pragma unroll
    for (int kt = 0; kt < 3; ++kt) {
        bf16x8 a = As[ar][kt * 4 + l4];
#pragma unroll
        for (int f = 0; f < 12; ++f) {
            bf16x8 b = Bs[f * 16 + l15][kt * 4 + l4];
            acc[f] = __builtin_amdgcn_mfma_f32_16x16x32_bf16(a, b, acc[f], 0, 0, 0);
        }
    }
    const int orow = row0 + wave * 16 + l4 * 4;
#pragma unroll
    for (int f = 0; f < 6; ++f) {
        const int col = f * 16 + l15;
        const float pbg = pwb[col];
        const float pbb = pwb[col + 96];
#pragma unroll
        for (int rr = 0; rr < 4; ++rr) {
            const float g = acc[f][rr] + pbg;
            const float bt = acc[f + 6][rr] + pbb;
            const float xe = (float)xemb[(size_t)(orow + rr) * MID_ + col];
            common[(size_t)(orow + rr) * MID_ + col] = (__bf16)(xe * (1.f + g) + bt);
        }
    }
}

// ---------------------------------------------------------------------------
// K_circ v2: circular 7x7 conv. dyn loaded from dyng (precomputed);
// guard-free sliding-window inner loop (22-wide circular window in regs,
// then 16x7 unguarded fma -- old guarded form wasted ~40% of VALU issue).
// ---------------------------------------------------------------------------
__global__ __launch_bounds__(192) void k_circ(const __bf16* __restrict__ common,
        const float* __restrict__ dyng, __bf16* __restrict__ outc) {
    __shared__ float dyn[49 * 96];
    const int t = threadIdx.x;
    const int b = blockIdx.x >> 7;
    const int h = (blockIdx.x >> 1) & 63;
    const int wslice = blockIdx.x & 1;
    const float* dsrc = dyng + (size_t)b * 4704;
    for (int idx = t; idx < 4704; idx += 192) dyn[idx] = dsrc[idx];
    __syncthreads();
    const int c = t % 96;
    const int wg = t / 96;
    const int wbase = wslice * 32 + wg * 16;
    const __bf16* cb = common + (size_t)b * 4096 * MID_ + c;
    float acc[16] = {};
#pragma unroll 1
    for (int p = 0; p < 7; ++p) {
        const int hh = (h + 3 - p) & 63;
        const __bf16* rp = cb + (size_t)hh * 64 * MID_;
        float dynr[7];
#pragma unroll
        for (int q = 0; q < 7; ++q) dynr[q] = dyn[(p * 7 + q) * 96 + c];
        float win[22];
#pragma unroll
        for (int i = 0; i < 22; ++i)
            win[i] = (float)rp[(size_t)((wbase - 3 + i) & 63) * MID_];
#pragma unroll
        for (int li = 0; li < 16; ++li) {
            float a = acc[li];
#pragma unroll
            for (int q = 0; q < 7; ++q) a += dynr[q] * win[li + 6 - q];
            acc[li] = a;
        }
    }
    const size_t obase = ((size_t)(b * 64 + h) * 64 + wbase) * MID_ + c;
#pragma unroll
    for (int li = 0; li < 16; ++li)
        outc[obase + (size_t)li * MID_] = (__bf16)acc[li];
}

// ---------------------------------------------------------------------------
// K_up: out = a_in[32768,96] @ up_w_bf16[768,96]^T + up_b + x  (fp32 out)
// ---------------------------------------------------------------------------
__global__ __launch_bounds__(256) void k_up(const __bf16* __restrict__ a_in,
        const __bf16* __restrict__ wbf, const float* __restrict__ upb,
        const float* __restrict__ x, float* __restrict__ out) {
    __shared__ bf16x8 As[128][13];
    __shared__ bf16x8 Ws[96][13];
    const int t = threadIdx.x;
    const int mt = blockIdx.x >> 3, nt = blockIdx.x & 7;
    const int row0 = mt * 128, col0 = nt * 96;
    for (int idx = t; idx < 1536; idx += 256) {
        const int rr = idx / 12, q = idx - rr * 12;
        As[rr][q] = *reinterpret_cast<const bf16x8*>(
            a_in + (size_t)(row0 + rr) * MID_ + q * 8);
    }
    for (int idx = t; idx < 1152; idx += 256) {
        const int rr = idx / 12, q = idx - rr * 12;
        Ws[rr][q] = *reinterpret_cast<const bf16x8*>(
            wbf + (size_t)(col0 + rr) * MID_ + q * 8);
    }
    __syncthreads();
    const int lane = t & 63, wave = t >> 6;
    const int l15 = lane & 15, l4 = lane >> 4;
    f32x4 acc[2][6] = {};
#pragma unroll
    for (int kt = 0; kt < 3; ++kt) {
        bf16x8 a0 = As[wave * 32 + l15][kt * 4 + l4];
        bf16x8 a1 = As[wave * 32 + 16 + l15][kt * 4 + l4];
#pragma unroll
        for (int f = 0; f < 6; ++f) {
            bf16x8 b = Ws[f * 16 + l15][kt * 4 + l4];
            acc[0][f] = __builtin_amdgcn_mfma_f32_16x16x32_bf16(a0, b, acc[0][f], 0, 0, 0);
            acc[1][f] = __builtin_amdgcn_mfma_f32_16x16x32_bf16(a1, b, acc[1][f], 0, 0, 0);
        }
    }
#pragma unroll
    for (int mr = 0; mr < 2; ++mr) {
        const int orow = row0 + wave * 32 + mr * 16 + l4 * 4;
#pragma unroll
        for (int f = 0; f < 6; ++f) {
            const int col = col0 + f * 16 + l15;
            const float ub = upb[col];
#pragma unroll
            for (int rr = 0; rr < 4; ++rr) {
                const size_t idx = (size_t)(orow + rr) * DIM_ + col;
                out[idx] = acc[mr][f][rr] + ub + x[idx];
            }
        }
    }
}

// ---------------------------------------------------------------------------
extern "C" void kernel_launch(void* const* d_in, const int* in_sizes, int n_in,
                              void* d_out, int out_size, void* d_ws, size_t ws_size,
                              hipStream_t stream) {
    (void)in_sizes; (void)n_in; (void)out_size; (void)ws_size;
    const float* x      = (const float*)d_in[0];
    const float* tt     = (const float*)d_in[1];
    const float* ln_w   = (const float*)d_in[2];
    const float* ln_b   = (const float*)d_in[3];
    const float* down_w = (const float*)d_in[4];
    const float* down_b = (const float*)d_in[5];
    const float* ln1_w  = (const float*)d_in[6];
    const float* ln1_b  = (const float*)d_in[7];
    const float* down1_w= (const float*)d_in[8];
    const float* down1_b= (const float*)d_in[9];
    const float* dw_w   = (const float*)d_in[10];
    const float* dw_b   = (const float*)d_in[11];
    const float* pw_w   = (const float*)d_in[12];
    const float* pw_b   = (const float*)d_in[13];
    const float* m1w    = (const float*)d_in[14];
    const float* m1b    = (const float*)d_in[15];
    const float* m2w    = (const float*)d_in[16];
    const float* m2b    = (const float*)d_in[17];
    const float* basis  = (const float*)d_in[18];
    const float* up_w   = (const float*)d_in[19];
    const float* up_b   = (const float*)d_in[20];
    float* out = (float*)d_out;
    char* ws = (char*)d_ws;

    // workspace layout (bytes)
    __bf16* wln_down  = (__bf16*)(ws + 0);          // 96*768*2  = 147456
    __bf16* wln_down1 = (__bf16*)(ws + 147456);
    __bf16* wbf_up    = (__bf16*)(ws + 294912);     // 768*96*2
    __bf16* wbf_pw    = (__bf16*)(ws + 442368);     // 192*96*2 = 36864
    float*  part      = (float*)(ws + 479232);      // 8*96*4 = 3072
    float*  wts       = (float*)(ws + 482304);      // 32*4
    float*  swcb      = (float*)(ws + 482560);      // 2*192*4 = 1536
    __bf16* x_emb     = (__bf16*)(ws + 524288);     // 32768*96*2 = 6291456
    __bf16* t_emb     = (__bf16*)(ws + 6815744);
    __bf16* ybuf      = (__bf16*)(ws + 13107200);
    __bf16* common    = (__bf16*)(ws + 19398656);
    __bf16* convout   = (__bf16*)(ws + 25690112);
    float*  dyng      = (float*)(ws + 31981568);    // 8*49*96*4 = 150528

    // opt-in to >64KB dynamic LDS for k_downf (not a stream op; capture-safe)
    (void)hipFuncSetAttribute((const void*)k_downf,
                              hipFuncAttributeMaxDynamicSharedMemorySize, 147456);

    k_prep<<<141, 256, 0, stream>>>(down_w, down_b, ln_w, ln_b,
                                    down1_w, down1_b, ln1_w, ln1_b,
                                    wln_down, wln_down1, swcb,
                                    up_w, pw_w, wbf_up, wbf_pw, part);
    k_downf<<<256, 1024, 147456, stream>>>(x, tt, wln_down, wln_down1, swcb,
                                           x_emb, t_emb, part);
    k_mlp<<<8, 128, 0, stream>>>(part, m1w, m1b, m2w, m2b, wts);
    k_dyn<<<147, 256, 0, stream>>>(wts, basis, dyng);
    k_dwconv<<<512, 256, 0, stream>>>(t_emb, dw_w, dw_b, ybuf);
    k_style<<<512, 256, 0, stream>>>(ybuf, wbf_pw, pw_b, x_emb, common);
    k_circ<<<1024, 192, 0, stream>>>(common, dyng, convout);
    k_up<<<2048, 256, 0, stream>>>(convout, wbf_up, up_b, x, out);
}